// Round 7
// baseline (647.941 us; speedup 1.0000x reference)
//
#include <hip/hip_runtime.h>
#include <hip/hip_bf16.h>
#include <stdint.h>

#define AS1 __attribute__((address_space(1)))
#define AS3 __attribute__((address_space(3)))

typedef __bf16 bf16x8 __attribute__((ext_vector_type(8)));
typedef __bf16 bf16x4 __attribute__((ext_vector_type(4)));
typedef float  f32x4  __attribute__((ext_vector_type(4)));

__device__ __forceinline__ void gld_lds16(const void* g, void* l) {
    __builtin_amdgcn_global_load_lds((AS1 void*)g, (AS3 void*)l, 16, 0, 0);
}

// ---------------------------------------------------------------------------
// XCD-aware tile remap (8 XCDs, linear bid & 7). Contiguous C region per XCD.
// ---------------------------------------------------------------------------
__device__ __forceinline__ void xcd_remap(int& bc, int& br) {
    const int GX = gridDim.x, GY = gridDim.y;
    const int L = blockIdx.y * GX + blockIdx.x;
    int rw, rh, nregx;
    if (GX >= 16 && (GX & 1) == 0 && (GY & 3) == 0) {
        rw = GX >> 1; rh = GY >> 2; nregx = 2;       // 2 x 4 regions
    } else if ((GY & 7) == 0) {
        rw = GX;      rh = GY >> 3; nregx = 1;       // 1 x 8 regions
    } else {
        bc = blockIdx.x; br = blockIdx.y; return;
    }
    const int xcd  = L & 7;
    const int slot = L >> 3;
    const int rx = xcd % nregx, ry = xcd / nregx;
    bc = rx * rw + slot % rw;
    br = ry * rh + slot / rw;
}

// ---------------------------------------------------------------------------
// PROVEN engine: NT GEMM 128x128 tile, BK=32, 256 threads, 2x2 waves,
// mfma 16x16x32 bf16, XOR-swizzled LDS, gld_lds16 staging, 4 blocks/CU
// (register-capped: 56 VGPR + 64 AGPR; launch_bounds(256,5) would spill acc).
// HISTORY: 256^2 8-phase schedules (R1-R3) all SLOWER (23-26% MfmaUtil vs
// 28.7%). PV split-K=4 (R6) regressed FF1 105->119us by dirtying the full
// 64MiB HB span with partials (cross-XCD dirty-line merge on FF1's writes).
// Keep partial footprint in the XB..VT span minimal.
// z-dim: A += z*sA, B += z*sB, C += z*sC, bias += z*sBias (QKV fuse/split-K)
// epilogue: 0 = +bias | 1 = *scale | 3 = +bias, fast GELU |
//           4 = E=exp(v*scale-8) store + per-row fp32 atomic rowsum
//               (softmax fused; normalization folded into LN via rowscale) |
//           5 = QKV fuse: z<2 as ep0; z==2 writes bias-added V TRANSPOSED
//               into (bf16*)rowsum as [2][1024][4096] (S=4096, D=1024 fixed)
// ---------------------------------------------------------------------------
__global__ __launch_bounds__(256, 4)
void gemm_nt(const __bf16* __restrict__ A, const __bf16* __restrict__ B,
             __bf16* __restrict__ C, const float* __restrict__ bias,
             float* __restrict__ rowsum,
             int K, int lda, int ldb, int ldc,
             long sA, long sB, long sC, long sBias,
             int ep, float scale)
{
    __shared__ __bf16 smA[2][4096];   // 2 x 128x32
    __shared__ __bf16 smB[2][4096];
    const int t  = threadIdx.x;
    const int l  = t & 63;
    const int w  = t >> 6;
    const int wm = w >> 1, wn = w & 1;
    const int lr = l & 15;
    const int lq = l >> 4;
    const long bz = blockIdx.z;
    int br, bc;
    xcd_remap(bc, br);

    const int swc = ((t & 3) ^ ((t >> 3) & 3)) * 8;
    const __bf16* ag = A + bz * sA + (size_t)(br * 128 + (t >> 2)) * lda + swc;
    const __bf16* bg = B + bz * sB + (size_t)(bc * 128 + (t >> 2)) * ldb + swc;
    const size_t a64 = (size_t)64 * lda, b64 = (size_t)64 * ldb;

    f32x4 acc[4][4];
    const f32x4 zero4 = {0.f, 0.f, 0.f, 0.f};
#pragma unroll
    for (int i = 0; i < 4; ++i)
#pragma unroll
        for (int j = 0; j < 4; ++j) acc[i][j] = zero4;

    const int paOff = (wm * 64 + lr) * 32 + ((lq ^ ((lr >> 1) & 3)) * 8);
    const int pbOff = (wn * 64 + lr) * 32 + ((lq ^ ((lr >> 1) & 3)) * 8);

    auto prefetch = [&](int b) {
        __bf16* la = &smA[b][t * 8];
        __bf16* lb = &smB[b][t * 8];
        gld_lds16(ag,       la);
        gld_lds16(ag + a64, la + 2048);
        gld_lds16(bg,       lb);
        gld_lds16(bg + b64, lb + 2048);
        ag += 32; bg += 32;
    };
    auto compute = [&](int b) {
        const __bf16* pa = &smA[b][paOff];
        const __bf16* pb = &smB[b][pbOff];
        bf16x8 af[4], bfr[4];
#pragma unroll
        for (int i = 0; i < 4; ++i) af[i]  = *(const bf16x8*)(pa + i * 16 * 32);
#pragma unroll
        for (int j = 0; j < 4; ++j) bfr[j] = *(const bf16x8*)(pb + j * 16 * 32);
#pragma unroll
        for (int i = 0; i < 4; ++i)
#pragma unroll
            for (int j = 0; j < 4; ++j)
                acc[i][j] = __builtin_amdgcn_mfma_f32_16x16x32_bf16(af[i], bfr[j], acc[i][j], 0, 0, 0);
    };

    const int nkt = K >> 5;          // always even here
    prefetch(0);
    for (int kt = 0; kt < nkt; kt += 2) {
        __syncthreads();             // tile kt ready; buf1 readers done
        if (kt + 1 < nkt) prefetch(1);
        compute(0);
        __syncthreads();             // tile kt+1 ready; buf0 readers done
        if (kt + 2 < nkt) prefetch(0);
        compute(1);
    }

    // C/D layout (m89-verified): col = lane&15, row = (lane>>4)*4 + reg
    const int r0 = br * 128 + wm * 64 + lq * 4;
    const int c0 = bc * 128 + wn * 64 + lr;
    C += bz * sC;
    const float* bs = bias ? bias + bz * sBias : nullptr;

    if (ep == 4) {
        // fused softmax numerator: E = exp(v*scale - 8); constant shift
        // cancels exactly at normalization (scores bounded, no row max
        // needed). fp32 row sums via 16-lane shfl_xor reduce + one
        // atomicAdd per row per wave.
#pragma unroll
        for (int i = 0; i < 4; ++i) {
            float rs4[4] = {0.f, 0.f, 0.f, 0.f};
#pragma unroll
            for (int j = 0; j < 4; ++j) {
                const int col = c0 + j * 16;
#pragma unroll
                for (int r = 0; r < 4; ++r) {
                    const long row = r0 + i * 16 + r;
                    const float e = __expf(acc[i][j][r] * scale - 8.0f);
                    C[row * (long)ldc + col] = (__bf16)e;
                    rs4[r] += e;
                }
            }
#pragma unroll
            for (int r = 0; r < 4; ++r) {
                float s = rs4[r];
                s += __shfl_xor(s, 1, 64);
                s += __shfl_xor(s, 2, 64);
                s += __shfl_xor(s, 4, 64);
                s += __shfl_xor(s, 8, 64);
                if (lr == 0) atomicAdd(&rowsum[r0 + i * 16 + r], s);
            }
        }
        return;
    }

    if (ep == 5 && bz == 2) {
        // V projection written TRANSPOSED: VT[b][d][s] = V[b*4096+s][d]+bv[d]
        // Block covers a 128(d) x 128(s) VT tile; every 64B line is fully
        // written collectively, so HBM write traffic is unchanged.
        __bf16* VT = (__bf16*)rowsum;
#pragma unroll
        for (int i = 0; i < 4; ++i) {
#pragma unroll
            for (int j = 0; j < 4; ++j) {
                const int col = c0 + j * 16;            // d
                const float bcol = bs ? bs[col] : 0.f;  // bv
#pragma unroll
                for (int r = 0; r < 4; ++r) {
                    const long row = r0 + i * 16 + r;   // token in [0, 8192)
                    const long b   = row >> 12;         // /4096 (S fixed)
                    const long s   = row & 4095;
                    VT[(b * 1024 + col) * 4096 + s] = (__bf16)(acc[i][j][r] + bcol);
                }
            }
        }
        return;
    }

#pragma unroll
    for (int i = 0; i < 4; ++i) {
#pragma unroll
        for (int j = 0; j < 4; ++j) {
            const int col = c0 + j * 16;
            const float bcol = (ep != 1 && bs) ? bs[col] : 0.f;
#pragma unroll
            for (int r = 0; r < 4; ++r) {
                const long row = r0 + i * 16 + r;
                const long idx = row * (long)ldc + col;
                const float v = acc[i][j][r];
                if (ep == 0 || ep == 5) {
                    C[idx] = (__bf16)(v + bcol);
                } else if (ep == 1) {
                    C[idx] = (__bf16)(v * scale);
                } else {
                    const float u = v + bcol;
                    const float z = 1.59576912f * (u + 0.044715f * u * u * u);
                    C[idx] = (__bf16)(u / (1.f + __expf(-z)));
                }
            }
        }
    }
}

// ---------------------------------------------------------------------------
__global__ __launch_bounds__(256)
void conv_bf16(const float* __restrict__ in, __bf16* __restrict__ out)
{
    const long i = (long)blockIdx.x * 256 + threadIdx.x;
    const float4 f = ((const float4*)in)[i];
    bf16x4 o = {(__bf16)f.x, (__bf16)f.y, (__bf16)f.z, (__bf16)f.w};
    ((bf16x4*)out)[i] = o;
}

// ---------------------------------------------------------------------------
// f32 [K,N] -> bf16 [N,K] transpose.
// ---------------------------------------------------------------------------
__global__ void tr_f32_bf16(const float* __restrict__ in, __bf16* __restrict__ out,
                            int K, int N)
{
    __shared__ float tl[32][33];
    const int x = threadIdx.x, y = threadIdx.y;
    const int n0 = blockIdx.x * 32, k0 = blockIdx.y * 32;
#pragma unroll
    for (int i = 0; i < 4; ++i)
        tl[y + 8 * i][x] = in[(size_t)(k0 + y + 8 * i) * N + n0 + x];
    __syncthreads();
#pragma unroll
    for (int i = 0; i < 4; ++i)
        out[(size_t)(n0 + y + 8 * i) * K + k0 + x] = (__bf16)tl[x][y + 8 * i];
}

// ---------------------------------------------------------------------------
// Three square f32 [D,D] -> bf16 [D,D] transposes in one dispatch (z picks
// the input pointer explicitly — no cross-allocation strides).
// ---------------------------------------------------------------------------
__global__ void tr3_f32_bf16(const float* __restrict__ in0,
                             const float* __restrict__ in1,
                             const float* __restrict__ in2,
                             __bf16* __restrict__ out, int D)
{
    const float* in = (blockIdx.z == 0) ? in0 : (blockIdx.z == 1) ? in1 : in2;
    out += (size_t)blockIdx.z * D * D;
    __shared__ float tl[32][33];
    const int x = threadIdx.x, y = threadIdx.y;
    const int n0 = blockIdx.x * 32, k0 = blockIdx.y * 32;
#pragma unroll
    for (int i = 0; i < 4; ++i)
        tl[y + 8 * i][x] = in[(size_t)(k0 + y + 8 * i) * D + n0 + x];
    __syncthreads();
#pragma unroll
    for (int i = 0; i < 4; ++i)
        out[(size_t)(n0 + y + 8 * i) * D + k0 + x] = (__bf16)tl[x][y + 8 * i];
}

// ---------------------------------------------------------------------------
// y = LayerNorm(a + P [+ lnb_col]) * gamma + beta ; row = 1024
// P = (b [+ b2 + b3 + b4]) * (1/rowscale[row] if rowscale)  -- softmax fold
// a: fp32 (af) or bf16 (ab); b..b4: bf16 partials; lnb: fp32 broadcast bias
// ---------------------------------------------------------------------------
__global__ __launch_bounds__(256)
void ln_residual(const float* __restrict__ af, const __bf16* __restrict__ ab,
                 const __bf16* __restrict__ bb, const __bf16* __restrict__ bb2,
                 const __bf16* __restrict__ bb3, const __bf16* __restrict__ bb4,
                 const float* __restrict__ lnb,
                 const float* __restrict__ rowscale,
                 const float* __restrict__ gamma, const float* __restrict__ beta,
                 float* __restrict__ outf, __bf16* __restrict__ outb)
{
    const long row = blockIdx.x;
    const int t = threadIdx.x;
    float x0, x1, x2, x3;
    if (af) {
        const float4 va = ((const float4*)(af + row * 1024))[t];
        x0 = va.x; x1 = va.y; x2 = va.z; x3 = va.w;
    } else {
        const bf16x4 va = ((const bf16x4*)(ab + row * 1024))[t];
        x0 = (float)va[0]; x1 = (float)va[1]; x2 = (float)va[2]; x3 = (float)va[3];
    }
    float p0, p1, p2, p3;
    {
        const bf16x4 vb = ((const bf16x4*)(bb + row * 1024))[t];
        p0 = (float)vb[0]; p1 = (float)vb[1]; p2 = (float)vb[2]; p3 = (float)vb[3];
    }
    if (bb2) {
        const bf16x4 vb = ((const bf16x4*)(bb2 + row * 1024))[t];
        p0 += (float)vb[0]; p1 += (float)vb[1]; p2 += (float)vb[2]; p3 += (float)vb[3];
    }
    if (bb3) {
        const bf16x4 vb = ((const bf16x4*)(bb3 + row * 1024))[t];
        p0 += (float)vb[0]; p1 += (float)vb[1]; p2 += (float)vb[2]; p3 += (float)vb[3];
    }
    if (bb4) {
        const bf16x4 vb = ((const bf16x4*)(bb4 + row * 1024))[t];
        p0 += (float)vb[0]; p1 += (float)vb[1]; p2 += (float)vb[2]; p3 += (float)vb[3];
    }
    if (rowscale) {
        const float inv = 1.f / rowscale[row];
        p0 *= inv; p1 *= inv; p2 *= inv; p3 *= inv;
    }
    x0 += p0; x1 += p1; x2 += p2; x3 += p3;
    if (lnb) {
        const float4 vb = ((const float4*)lnb)[t];
        x0 += vb.x; x1 += vb.y; x2 += vb.z; x3 += vb.w;
    }
    float s = x0 + x1 + x2 + x3;
    float q = x0 * x0 + x1 * x1 + x2 * x2 + x3 * x3;
#pragma unroll
    for (int o = 32; o; o >>= 1) { s += __shfl_down(s, o, 64); q += __shfl_down(q, o, 64); }
    __shared__ float rs[4], rq[4];
    if ((t & 63) == 0) { rs[t >> 6] = s; rq[t >> 6] = q; }
    __syncthreads();
    s = rs[0] + rs[1] + rs[2] + rs[3];
    q = rq[0] + rq[1] + rq[2] + rq[3];
    const float mu  = s * (1.f / 1024.f);
    const float inv = rsqrtf(q * (1.f / 1024.f) - mu * mu + 1e-5f);
    const float4 g  = ((const float4*)gamma)[t];
    const float4 be = ((const float4*)beta)[t];
    const float y0 = (x0 - mu) * inv * g.x + be.x;
    const float y1 = (x1 - mu) * inv * g.y + be.y;
    const float y2 = (x2 - mu) * inv * g.z + be.z;
    const float y3 = (x3 - mu) * inv * g.w + be.w;
    if (outf) ((float4*)(outf + row * 1024))[t] = make_float4(y0, y1, y2, y3);
    if (outb) {
        bf16x4 o4 = {(__bf16)y0, (__bf16)y1, (__bf16)y2, (__bf16)y3};
        ((bf16x4*)outb)[row * 256 + t] = o4;
    }
}

// diagnostic / fill: out[i] = v  (also used to zero the rowsum array)
__global__ __launch_bounds__(256)
void fill_diag(float* __restrict__ out, float v, long n)
{
    const long i = (long)blockIdx.x * 256 + threadIdx.x;
    if (i < n) out[i] = v;
}

// ---------------------------------------------------------------------------
extern "C" void kernel_launch(void* const* d_in, const int* in_sizes, int n_in,
                              void* d_out, int out_size, void* d_ws, size_t ws_size,
                              hipStream_t stream)
{
    const float* X  = (const float*)d_in[0];
    const float* Wq = (const float*)d_in[1];
    const float* bq = (const float*)d_in[2];
    const float* Wk = (const float*)d_in[3];
    const float* bk = (const float*)d_in[4];
    const float* Wv = (const float*)d_in[5];
    const float* bv = (const float*)d_in[6];
    const float* W1 = (const float*)d_in[7];
    const float* b1 = (const float*)d_in[8];
    const float* W2 = (const float*)d_in[9];
    const float* b2 = (const float*)d_in[10];
    const float* gamma = (const float*)d_in[11];
    const float* beta  = (const float*)d_in[12];
    float* out = (float*)d_out;

    const int S = 4096, D = 1024, H = 4096;
    const int M = 2 * S;
    const size_t MB = 1ull << 20;

    // ---- workspace layout (128 MiB tier1 / 112 MiB tier2) ----
    // 0:W1T(8) 8:W2T(8) 16:XB/P0 32:QP 48:KP 64:VP=P1 80:VT->FF
    // 16..80: HB (64 MiB, after LN6)  96: WQT+BIAS -> SL -> XLNB  112: FF2
    // V^T is produced directly by the QKV epilogue (ep=5) into VT; the VP
    // region is therefore free and hosts PV partial 1 (P0 = dead XB).
    // Only 32 MiB of the future-HB span gets partial-dirtied (R6 lesson:
    // dirtying all 64 MiB slowed FF1's writes by ~13%).
    // RS (fp32 row sums, 32 KB) lives in d_out scratch: d_out is first
    // written by the final LN, after RS's last read at LN6.
    char* ws = (char*)d_ws;
    __bf16* W1T = (__bf16*)(ws);
    __bf16* W2T = (__bf16*)(ws + 8 * MB);
    __bf16* XB  = (__bf16*)(ws + 16 * MB);
    __bf16* P0  = XB;
    __bf16* QP  = (__bf16*)(ws + 32 * MB);
    __bf16* KP  = (__bf16*)(ws + 48 * MB);
    __bf16* VP  = (__bf16*)(ws + 64 * MB);   // PV partial 1
    __bf16* VT  = (__bf16*)(ws + 80 * MB);
    __bf16* FF  = VT;
    __bf16* HB  = XB;                        // 64 MiB span, used post-LN6
    __bf16* SL  = (__bf16*)(ws + 96 * MB);
    __bf16* WQT = (__bf16*)(ws + 96 * MB);
    float*  BIAS= (float*)(ws + 96 * MB + 6 * MB);
    __bf16* XLNB= (__bf16*)(ws + 96 * MB);
    __bf16* FF2 = (__bf16*)(ws + 112 * MB);
    float*  RS  = out;                       // 8192 fp32, d_out as scratch

    int Rs;
    if (ws_size >= 128 * MB)      Rs = 4096;
    else if (ws_size >= 112 * MB) Rs = 2048;
    else {
        fill_diag<<<dim3((out_size + 255) / 256), dim3(256), 0, stream>>>(
            out, (float)(ws_size >> 20), out_size);
        return;
    }

    const dim3 t256(256);
    const dim3 t32x8(32, 8);

    // stage 0: dtype prep (Wq/Wk/Wv transposes fused via explicit 3-ptr z)
    conv_bf16<<<dim3(M * D / 1024), t256, 0, stream>>>(X, XB);
    tr3_f32_bf16<<<dim3(D / 32, D / 32, 3), t32x8, 0, stream>>>(Wq, Wk, Wv, WQT, D);
    tr_f32_bf16<<<dim3(H / 32, D / 32), t32x8, 0, stream>>>(W1, W1T, D, H);
    tr_f32_bf16<<<dim3(D / 32, H / 32), t32x8, 0, stream>>>(W2, W2T, H, D);
    hipMemcpyAsync(BIAS,         bq, D * 4, hipMemcpyDeviceToDevice, stream);
    hipMemcpyAsync(BIAS + D,     bk, D * 4, hipMemcpyDeviceToDevice, stream);
    hipMemcpyAsync(BIAS + 2 * D, bv, D * 4, hipMemcpyDeviceToDevice, stream);

    // stage 1: fused QKV projections, z = {q,k,v}; ep=5 writes V^T directly
    // into VT (z=2), Q/K normally into QP/KP. tr_bf16 dispatch eliminated.
    gemm_nt<<<dim3(D / 128, M / 128, 3), t256, 0, stream>>>(
        XB, WQT, QP, BIAS, (float*)VT, D, D, D, D,
        0, (long)D * D, (long)M * D, D, 5, 0.f);

    // zero fused-softmax row sums (d_out scratch)
    fill_diag<<<dim3(M / 256), t256, 0, stream>>>(RS, 0.f, M);

    // stages 3-5: attention via score slab (quirk: queries<-KP, keys<-QP)
    // QK^T ep=4: E=exp(s/32 - 8) + fp32 row sums (softmax pass eliminated).
    // PV split-K=2 (R4-verified config): partials -> P0(XB) / VP.
    const long sCpv = (long)(VP - P0);
    for (int b = 0; b < 2; ++b) {
        for (int c = 0; c < S / Rs; ++c) {
            const __bf16* Ak = KP + (size_t)(b * S + c * Rs) * D;
            gemm_nt<<<dim3(S / 128, Rs / 128), t256, 0, stream>>>(
                Ak, QP + (size_t)b * S * D, SL, nullptr, RS + (size_t)b * S + c * Rs,
                D, D, D, S, 0, 0, 0, 0, 4, 0.03125f);
            gemm_nt<<<dim3(D / 128, Rs / 128, 2), t256, 0, stream>>>(
                SL, VT + (size_t)b * D * S, P0 + (size_t)(b * S + c * Rs) * D,
                nullptr, nullptr,
                S / 2, S, S, D, S / 2, S / 2, sCpv, 0, 0, 0.f);
        }
    }

    // stage 6: x = LN(input + (P0 + P1)/rowsum) -> bf16
    ln_residual<<<dim3(M), t256, 0, stream>>>(
        X, nullptr, P0, VP, nullptr, nullptr, nullptr, RS, gamma, beta, nullptr, XLNB);

    // stage 7: h = gelu(x @ W1 + b1)
    gemm_nt<<<dim3(H / 128, M / 128), t256, 0, stream>>>(
        XLNB, W1T, HB, b1, nullptr, D, D, D, H, 0, 0, 0, 0, 3, 0.f);

    // stage 8 + 9
    if (Rs == 4096) {
        // split-K=2: partials to FF / FF2 (no bias; b2 added in LN)
        gemm_nt<<<dim3(D / 128, M / 128, 2), t256, 0, stream>>>(
            HB, W2T, FF, nullptr, nullptr, H / 2, H, H, D,
            H / 2, H / 2, (long)(FF2 - FF), 0, 1, 1.0f);
        ln_residual<<<dim3(M), t256, 0, stream>>>(
            nullptr, XLNB, FF, FF2, nullptr, nullptr, b2, nullptr, gamma, beta, out, nullptr);
    } else {
        gemm_nt<<<dim3(D / 128, M / 128), t256, 0, stream>>>(
            HB, W2T, FF, b2, nullptr, H, H, H, D, 0, 0, 0, 0, 0, 0.f);
        ln_residual<<<dim3(M), t256, 0, stream>>>(
            nullptr, XLNB, FF, nullptr, nullptr, nullptr, nullptr, nullptr, gamma, beta, out, nullptr);
    }
}

// Round 8
// 614.806 us; speedup vs baseline: 1.0539x; 1.0539x over previous
//
#include <hip/hip_runtime.h>
#include <hip/hip_bf16.h>
#include <stdint.h>

#define AS1 __attribute__((address_space(1)))
#define AS3 __attribute__((address_space(3)))

typedef __bf16 bf16x8 __attribute__((ext_vector_type(8)));
typedef __bf16 bf16x4 __attribute__((ext_vector_type(4)));
typedef float  f32x4  __attribute__((ext_vector_type(4)));

__device__ __forceinline__ void gld_lds16(const void* g, void* l) {
    __builtin_amdgcn_global_load_lds((AS1 void*)g, (AS3 void*)l, 16, 0, 0);
}

// ---------------------------------------------------------------------------
// XCD-aware tile remap (8 XCDs, linear bid & 7). Contiguous C region per XCD.
// ---------------------------------------------------------------------------
__device__ __forceinline__ void xcd_remap(int& bc, int& br) {
    const int GX = gridDim.x, GY = gridDim.y;
    const int L = blockIdx.y * GX + blockIdx.x;
    int rw, rh, nregx;
    if (GX >= 16 && (GX & 1) == 0 && (GY & 3) == 0) {
        rw = GX >> 1; rh = GY >> 2; nregx = 2;       // 2 x 4 regions
    } else if ((GY & 7) == 0) {
        rw = GX;      rh = GY >> 3; nregx = 1;       // 1 x 8 regions
    } else {
        bc = blockIdx.x; br = blockIdx.y; return;
    }
    const int xcd  = L & 7;
    const int slot = L >> 3;
    const int rx = xcd % nregx, ry = xcd / nregx;
    bc = rx * rw + slot % rw;
    br = ry * rh + slot / rw;
}

// ---------------------------------------------------------------------------
// PROVEN engine: NT GEMM 128x128 tile, BK=32, 256 threads, 2x2 waves,
// mfma 16x16x32 bf16, XOR-swizzled LDS, gld_lds16 staging, 4 blocks/CU.
// HISTORY: 256^2 schedules (R1-R3) slower; PV partials dirtying the full HB
// span (R6) regressed FF1 writes 105->119us; V^T scatter epilogue (R7)
// regressed QKV 78->105us (64 lines touched per store instr). Keep epilogue
// stores lane-contiguous; keep partial footprint in XB..VT span <= 32 MiB;
// every dispatch >= 1024 blocks (2/CU runs at ~490 TF vs ~660).
// z-dim: A += z*sA, B += z*sB, C += z*sC, bias += z*sBias (QKV fuse/split-K)
// epilogue: 0 = +bias | 1 = *scale | 3 = +bias, fast GELU |
//           4 = E=exp(v*scale-8) store + per-row fp32 atomic rowsum
//               (softmax fused; normalization folded into LN via rowscale) |
//           6 = dual-slab PV: z=(b<<1)|ks; A = (b ? Aalt : A) + ks*sA,
//               B += b*sB + ks*sA, C += ks*sC + b*sBias; plain store.
// ---------------------------------------------------------------------------
__global__ __launch_bounds__(256, 4)
void gemm_nt(const __bf16* __restrict__ A, const __bf16* __restrict__ B,
             __bf16* __restrict__ C, const float* __restrict__ bias,
             float* __restrict__ rowsum, const __bf16* __restrict__ Aalt,
             int K, int lda, int ldb, int ldc,
             long sA, long sB, long sC, long sBias,
             int ep, float scale)
{
    __shared__ __bf16 smA[2][4096];   // 2 x 128x32
    __shared__ __bf16 smB[2][4096];
    const int t  = threadIdx.x;
    const int l  = t & 63;
    const int w  = t >> 6;
    const int wm = w >> 1, wn = w & 1;
    const int lr = l & 15;
    const int lq = l >> 4;
    const long bz = blockIdx.z;
    int br, bc;
    xcd_remap(bc, br);

    const __bf16* Ae = A;
    long aO, bO, cO;
    if (ep == 6) {
        const long b = bz >> 1, ks = bz & 1;
        Ae = b ? Aalt : A;
        aO = ks * sA;                 // sA = K-offset (elems) per split
        bO = b * sB + ks * sA;
        cO = ks * sC + b * sBias;     // sBias reused as batch-C stride
    } else {
        aO = bz * sA; bO = bz * sB; cO = bz * sC;
    }

    const int swc = ((t & 3) ^ ((t >> 3) & 3)) * 8;
    const __bf16* ag = Ae + aO + (size_t)(br * 128 + (t >> 2)) * lda + swc;
    const __bf16* bg = B  + bO + (size_t)(bc * 128 + (t >> 2)) * ldb + swc;
    const size_t a64 = (size_t)64 * lda, b64 = (size_t)64 * ldb;

    f32x4 acc[4][4];
    const f32x4 zero4 = {0.f, 0.f, 0.f, 0.f};
#pragma unroll
    for (int i = 0; i < 4; ++i)
#pragma unroll
        for (int j = 0; j < 4; ++j) acc[i][j] = zero4;

    const int paOff = (wm * 64 + lr) * 32 + ((lq ^ ((lr >> 1) & 3)) * 8);
    const int pbOff = (wn * 64 + lr) * 32 + ((lq ^ ((lr >> 1) & 3)) * 8);

    auto prefetch = [&](int b) {
        __bf16* la = &smA[b][t * 8];
        __bf16* lb = &smB[b][t * 8];
        gld_lds16(ag,       la);
        gld_lds16(ag + a64, la + 2048);
        gld_lds16(bg,       lb);
        gld_lds16(bg + b64, lb + 2048);
        ag += 32; bg += 32;
    };
    auto compute = [&](int b) {
        const __bf16* pa = &smA[b][paOff];
        const __bf16* pb = &smB[b][pbOff];
        bf16x8 af[4], bfr[4];
#pragma unroll
        for (int i = 0; i < 4; ++i) af[i]  = *(const bf16x8*)(pa + i * 16 * 32);
#pragma unroll
        for (int j = 0; j < 4; ++j) bfr[j] = *(const bf16x8*)(pb + j * 16 * 32);
#pragma unroll
        for (int i = 0; i < 4; ++i)
#pragma unroll
            for (int j = 0; j < 4; ++j)
                acc[i][j] = __builtin_amdgcn_mfma_f32_16x16x32_bf16(af[i], bfr[j], acc[i][j], 0, 0, 0);
    };

    const int nkt = K >> 5;          // always even here
    prefetch(0);
    for (int kt = 0; kt < nkt; kt += 2) {
        __syncthreads();             // tile kt ready; buf1 readers done
        if (kt + 1 < nkt) prefetch(1);
        compute(0);
        __syncthreads();             // tile kt+1 ready; buf0 readers done
        if (kt + 2 < nkt) prefetch(0);
        compute(1);
    }

    // C/D layout (m89-verified): col = lane&15, row = (lane>>4)*4 + reg
    const int r0 = br * 128 + wm * 64 + lq * 4;
    const int c0 = bc * 128 + wn * 64 + lr;
    C += cO;
    const float* bs = bias ? bias + bz * sBias : nullptr;

    if (ep == 4) {
        // fused softmax numerator: E = exp(v*scale - 8); constant shift
        // cancels exactly at normalization (scores bounded, no row max
        // needed). fp32 row sums via 16-lane shfl_xor reduce + one
        // atomicAdd per row per wave.
#pragma unroll
        for (int i = 0; i < 4; ++i) {
            float rs4[4] = {0.f, 0.f, 0.f, 0.f};
#pragma unroll
            for (int j = 0; j < 4; ++j) {
                const int col = c0 + j * 16;
#pragma unroll
                for (int r = 0; r < 4; ++r) {
                    const long row = r0 + i * 16 + r;
                    const float e = __expf(acc[i][j][r] * scale - 8.0f);
                    C[row * (long)ldc + col] = (__bf16)e;
                    rs4[r] += e;
                }
            }
#pragma unroll
            for (int r = 0; r < 4; ++r) {
                float s = rs4[r];
                s += __shfl_xor(s, 1, 64);
                s += __shfl_xor(s, 2, 64);
                s += __shfl_xor(s, 4, 64);
                s += __shfl_xor(s, 8, 64);
                if (lr == 0) atomicAdd(&rowsum[r0 + i * 16 + r], s);
            }
        }
        return;
    }

#pragma unroll
    for (int i = 0; i < 4; ++i) {
#pragma unroll
        for (int j = 0; j < 4; ++j) {
            const int col = c0 + j * 16;
            const float bcol = (ep == 0 && bs) ? bs[col] : (ep == 3 && bs) ? bs[col] : 0.f;
#pragma unroll
            for (int r = 0; r < 4; ++r) {
                const long row = r0 + i * 16 + r;
                const long idx = row * (long)ldc + col;
                const float v = acc[i][j][r];
                if (ep == 0 || ep == 6) {
                    C[idx] = (__bf16)(v + bcol);
                } else if (ep == 1) {
                    C[idx] = (__bf16)(v * scale);
                } else {
                    const float u = v + bcol;
                    const float z = 1.59576912f * (u + 0.044715f * u * u * u);
                    C[idx] = (__bf16)(u / (1.f + __expf(-z)));
                }
            }
        }
    }
}

// ---------------------------------------------------------------------------
__global__ __launch_bounds__(256)
void conv_bf16(const float* __restrict__ in, __bf16* __restrict__ out)
{
    const long i = (long)blockIdx.x * 256 + threadIdx.x;
    const float4 f = ((const float4*)in)[i];
    bf16x4 o = {(__bf16)f.x, (__bf16)f.y, (__bf16)f.z, (__bf16)f.w};
    ((bf16x4*)out)[i] = o;
}

// ---------------------------------------------------------------------------
// f32 [K,N] -> bf16 [N,K] transpose.
// ---------------------------------------------------------------------------
__global__ void tr_f32_bf16(const float* __restrict__ in, __bf16* __restrict__ out,
                            int K, int N)
{
    __shared__ float tl[32][33];
    const int x = threadIdx.x, y = threadIdx.y;
    const int n0 = blockIdx.x * 32, k0 = blockIdx.y * 32;
#pragma unroll
    for (int i = 0; i < 4; ++i)
        tl[y + 8 * i][x] = in[(size_t)(k0 + y + 8 * i) * N + n0 + x];
    __syncthreads();
#pragma unroll
    for (int i = 0; i < 4; ++i)
        out[(size_t)(n0 + y + 8 * i) * K + k0 + x] = (__bf16)tl[x][y + 8 * i];
}

// ---------------------------------------------------------------------------
// Three square f32 [D,D] -> bf16 [D,D] transposes in one dispatch (z picks
// the input pointer explicitly — no cross-allocation strides).
// ---------------------------------------------------------------------------
__global__ void tr3_f32_bf16(const float* __restrict__ in0,
                             const float* __restrict__ in1,
                             const float* __restrict__ in2,
                             __bf16* __restrict__ out, int D)
{
    const float* in = (blockIdx.z == 0) ? in0 : (blockIdx.z == 1) ? in1 : in2;
    out += (size_t)blockIdx.z * D * D;
    __shared__ float tl[32][33];
    const int x = threadIdx.x, y = threadIdx.y;
    const int n0 = blockIdx.x * 32, k0 = blockIdx.y * 32;
#pragma unroll
    for (int i = 0; i < 4; ++i)
        tl[y + 8 * i][x] = in[(size_t)(k0 + y + 8 * i) * D + n0 + x];
    __syncthreads();
#pragma unroll
    for (int i = 0; i < 4; ++i)
        out[(size_t)(n0 + y + 8 * i) * D + k0 + x] = (__bf16)tl[x][y + 8 * i];
}

// ---------------------------------------------------------------------------
__global__ void tr_bf16(const __bf16* __restrict__ in, __bf16* __restrict__ out,
                        int R, int C)
{
    in  += (size_t)blockIdx.z * R * C;
    out += (size_t)blockIdx.z * R * C;
    __shared__ __bf16 tl[32][33];
    const int x = threadIdx.x, y = threadIdx.y;
    const int c0 = blockIdx.x * 32, r0 = blockIdx.y * 32;
#pragma unroll
    for (int i = 0; i < 4; ++i)
        tl[y + 8 * i][x] = in[(size_t)(r0 + y + 8 * i) * C + c0 + x];
    __syncthreads();
#pragma unroll
    for (int i = 0; i < 4; ++i)
        out[(size_t)(c0 + y + 8 * i) * R + r0 + x] = tl[x][y + 8 * i];
}

// ---------------------------------------------------------------------------
// y = LayerNorm(a + P [+ lnb_col]) * gamma + beta ; row = 1024
// P = (b [+ b2 + b3 + b4]) * (1/rowscale[row] if rowscale)  -- softmax fold
// ---------------------------------------------------------------------------
__global__ __launch_bounds__(256)
void ln_residual(const float* __restrict__ af, const __bf16* __restrict__ ab,
                 const __bf16* __restrict__ bb, const __bf16* __restrict__ bb2,
                 const __bf16* __restrict__ bb3, const __bf16* __restrict__ bb4,
                 const float* __restrict__ lnb,
                 const float* __restrict__ rowscale,
                 const float* __restrict__ gamma, const float* __restrict__ beta,
                 float* __restrict__ outf, __bf16* __restrict__ outb)
{
    const long row = blockIdx.x;
    const int t = threadIdx.x;
    float x0, x1, x2, x3;
    if (af) {
        const float4 va = ((const float4*)(af + row * 1024))[t];
        x0 = va.x; x1 = va.y; x2 = va.z; x3 = va.w;
    } else {
        const bf16x4 va = ((const bf16x4*)(ab + row * 1024))[t];
        x0 = (float)va[0]; x1 = (float)va[1]; x2 = (float)va[2]; x3 = (float)va[3];
    }
    float p0, p1, p2, p3;
    {
        const bf16x4 vb = ((const bf16x4*)(bb + row * 1024))[t];
        p0 = (float)vb[0]; p1 = (float)vb[1]; p2 = (float)vb[2]; p3 = (float)vb[3];
    }
    if (bb2) {
        const bf16x4 vb = ((const bf16x4*)(bb2 + row * 1024))[t];
        p0 += (float)vb[0]; p1 += (float)vb[1]; p2 += (float)vb[2]; p3 += (float)vb[3];
    }
    if (bb3) {
        const bf16x4 vb = ((const bf16x4*)(bb3 + row * 1024))[t];
        p0 += (float)vb[0]; p1 += (float)vb[1]; p2 += (float)vb[2]; p3 += (float)vb[3];
    }
    if (bb4) {
        const bf16x4 vb = ((const bf16x4*)(bb4 + row * 1024))[t];
        p0 += (float)vb[0]; p1 += (float)vb[1]; p2 += (float)vb[2]; p3 += (float)vb[3];
    }
    if (rowscale) {
        const float inv = 1.f / rowscale[row];
        p0 *= inv; p1 *= inv; p2 *= inv; p3 *= inv;
    }
    x0 += p0; x1 += p1; x2 += p2; x3 += p3;
    if (lnb) {
        const float4 vb = ((const float4*)lnb)[t];
        x0 += vb.x; x1 += vb.y; x2 += vb.z; x3 += vb.w;
    }
    float s = x0 + x1 + x2 + x3;
    float q = x0 * x0 + x1 * x1 + x2 * x2 + x3 * x3;
#pragma unroll
    for (int o = 32; o; o >>= 1) { s += __shfl_down(s, o, 64); q += __shfl_down(q, o, 64); }
    __shared__ float rs[4], rq[4];
    if ((t & 63) == 0) { rs[t >> 6] = s; rq[t >> 6] = q; }
    __syncthreads();
    s = rs[0] + rs[1] + rs[2] + rs[3];
    q = rq[0] + rq[1] + rq[2] + rq[3];
    const float mu  = s * (1.f / 1024.f);
    const float inv = rsqrtf(q * (1.f / 1024.f) - mu * mu + 1e-5f);
    const float4 g  = ((const float4*)gamma)[t];
    const float4 be = ((const float4*)beta)[t];
    const float y0 = (x0 - mu) * inv * g.x + be.x;
    const float y1 = (x1 - mu) * inv * g.y + be.y;
    const float y2 = (x2 - mu) * inv * g.z + be.z;
    const float y3 = (x3 - mu) * inv * g.w + be.w;
    if (outf) ((float4*)(outf + row * 1024))[t] = make_float4(y0, y1, y2, y3);
    if (outb) {
        bf16x4 o4 = {(__bf16)y0, (__bf16)y1, (__bf16)y2, (__bf16)y3};
        ((bf16x4*)outb)[row * 256 + t] = o4;
    }
}

// diagnostic / fill: out[i] = v  (also used to zero the rowsum array)
__global__ __launch_bounds__(256)
void fill_diag(float* __restrict__ out, float v, long n)
{
    const long i = (long)blockIdx.x * 256 + threadIdx.x;
    if (i < n) out[i] = v;
}

// ---------------------------------------------------------------------------
extern "C" void kernel_launch(void* const* d_in, const int* in_sizes, int n_in,
                              void* d_out, int out_size, void* d_ws, size_t ws_size,
                              hipStream_t stream)
{
    const float* X  = (const float*)d_in[0];
    const float* Wq = (const float*)d_in[1];
    const float* bq = (const float*)d_in[2];
    const float* Wk = (const float*)d_in[3];
    const float* bk = (const float*)d_in[4];
    const float* Wv = (const float*)d_in[5];
    const float* bv = (const float*)d_in[6];
    const float* W1 = (const float*)d_in[7];
    const float* b1 = (const float*)d_in[8];
    const float* W2 = (const float*)d_in[9];
    const float* b2 = (const float*)d_in[10];
    const float* gamma = (const float*)d_in[11];
    const float* beta  = (const float*)d_in[12];
    float* out = (float*)d_out;

    const int S = 4096, D = 1024, H = 4096;
    const int M = 2 * S;
    const size_t MB = 1ull << 20;

    // ---- workspace layout (128 MiB tier1 / 112 MiB tier2) ----
    // 0:W1T(8) 8:W2T(8) 16:XB/P0 32:QP/P1 48:KP 64:VP(->RS tier1) 80:VT->FF
    // 16..80: HB (64 MiB, after LN6)  96: WQT -> SL0 -> XLNB  112: FF2
    // Tier1 attention: SL0 = ws+96 (batch 0 scores), SL1 = d_out (batch 1
    // scores; 32 MiB exact). PV runs ONCE: grid z=4 (batch x splitK) = 1024
    // blocks (4/CU). Partials -> P0(XB) + QP (dead after QK b1). Dirty HB
    // span = 32 MiB (R6 lesson: 64 MiB dirty costs FF1 ~14 us).
    // RS (fp32 row sums, 32 KB) -> VP base (dead after tr_bf16).
    char* ws = (char*)d_ws;
    __bf16* W1T = (__bf16*)(ws);
    __bf16* W2T = (__bf16*)(ws + 8 * MB);
    __bf16* XB  = (__bf16*)(ws + 16 * MB);
    __bf16* P0  = XB;
    __bf16* QP  = (__bf16*)(ws + 32 * MB);
    __bf16* KP  = (__bf16*)(ws + 48 * MB);
    __bf16* VP  = (__bf16*)(ws + 64 * MB);
    __bf16* VT  = (__bf16*)(ws + 80 * MB);
    __bf16* FF  = VT;
    __bf16* HB  = XB;                        // 64 MiB span, used post-LN6
    __bf16* SL0 = (__bf16*)(ws + 96 * MB);
    __bf16* WQT = (__bf16*)(ws + 96 * MB);
    float*  BIAS= (float*)(ws + 96 * MB + 6 * MB);
    __bf16* XLNB= (__bf16*)(ws + 96 * MB);
    __bf16* FF2 = (__bf16*)(ws + 112 * MB);
    __bf16* SL1 = (__bf16*)out;              // 32 MiB scratch slab (tier1)

    int Rs;
    if (ws_size >= 128 * MB)      Rs = 4096;
    else if (ws_size >= 112 * MB) Rs = 2048;
    else {
        fill_diag<<<dim3((out_size + 255) / 256), dim3(256), 0, stream>>>(
            out, (float)(ws_size >> 20), out_size);
        return;
    }
    float* RS = (Rs == 4096) ? (float*)VP : out;  // tier2 keeps RS in d_out

    const dim3 t256(256);
    const dim3 t32x8(32, 8);

    // stage 0: dtype prep
    conv_bf16<<<dim3(M * D / 1024), t256, 0, stream>>>(X, XB);
    tr3_f32_bf16<<<dim3(D / 32, D / 32, 3), t32x8, 0, stream>>>(Wq, Wk, Wv, WQT, D);
    tr_f32_bf16<<<dim3(H / 32, D / 32), t32x8, 0, stream>>>(W1, W1T, D, H);
    tr_f32_bf16<<<dim3(D / 32, H / 32), t32x8, 0, stream>>>(W2, W2T, H, D);
    hipMemcpyAsync(BIAS,         bq, D * 4, hipMemcpyDeviceToDevice, stream);
    hipMemcpyAsync(BIAS + D,     bk, D * 4, hipMemcpyDeviceToDevice, stream);
    hipMemcpyAsync(BIAS + 2 * D, bv, D * 4, hipMemcpyDeviceToDevice, stream);

    // stage 1: fused QKV projections, z = {q,k,v} -> QP/KP/VP
    gemm_nt<<<dim3(D / 128, M / 128, 3), t256, 0, stream>>>(
        XB, WQT, QP, BIAS, nullptr, nullptr, D, D, D, D,
        0, (long)D * D, (long)M * D, D, 0, 0.f);

    // stage 2: V^T per batch [D,S]
    tr_bf16<<<dim3(D / 32, S / 32, 2), t32x8, 0, stream>>>(VP, VT, S, D);

    // zero fused-softmax row sums (VP dead after transpose / d_out tier2)
    fill_diag<<<dim3(M / 256), t256, 0, stream>>>(RS, 0.f, M);

    // stages 3-5: attention (quirk: queries<-KP, keys<-QP); QK^T ep=4 fuses
    // exp + rowsum (softmax pass eliminated; normalization folded into LN6).
    if (Rs == 4096) {
        // QK b0 -> SL0, QK b1 -> SL1 (d_out); both slabs live simultaneously
        gemm_nt<<<dim3(S / 128, S / 128), t256, 0, stream>>>(
            KP, QP, SL0, nullptr, RS, nullptr,
            D, D, D, S, 0, 0, 0, 0, 4, 0.03125f);
        gemm_nt<<<dim3(S / 128, S / 128), t256, 0, stream>>>(
            KP + (size_t)S * D, QP + (size_t)S * D, SL1, nullptr, RS + S, nullptr,
            D, D, D, S, 0, 0, 0, 0, 4, 0.03125f);
        // PV combined, ep=6: z=(b<<1)|ks -> 1024 blocks (4/CU).
        // A = SL0/SL1 + ks*2048; B = VT + b*DS + ks*2048; C = P_ks + b*SD.
        gemm_nt<<<dim3(D / 128, S / 128, 4), t256, 0, stream>>>(
            SL0, VT, P0, nullptr, nullptr, SL1,
            S / 2, S, S, D,
            (long)(S / 2), (long)D * S, (long)(QP - P0), (long)S * D,
            6, 0.f);
    } else {
        // tier2 fallback: per-chunk QK -> SL0 (16 MiB slab), PV split-K=2
        // partials -> P0 / VP (RS lives in d_out here).
        const long sCpv = (long)(VP - P0);
        for (int b = 0; b < 2; ++b) {
            for (int c = 0; c < S / Rs; ++c) {
                const __bf16* Ak = KP + (size_t)(b * S + c * Rs) * D;
                gemm_nt<<<dim3(S / 128, Rs / 128), t256, 0, stream>>>(
                    Ak, QP + (size_t)b * S * D, SL0, nullptr,
                    RS + (size_t)b * S + c * Rs, nullptr,
                    D, D, D, S, 0, 0, 0, 0, 4, 0.03125f);
                gemm_nt<<<dim3(D / 128, Rs / 128, 2), t256, 0, stream>>>(
                    SL0, VT + (size_t)b * D * S, P0 + (size_t)(b * S + c * Rs) * D,
                    nullptr, nullptr, nullptr,
                    S / 2, S, S, D, S / 2, S / 2, sCpv, 0, 0, 0.f);
            }
        }
    }

    // stage 6: x = LN(input + (P0 + P1)/rowsum) -> bf16
    if (Rs == 4096) {
        ln_residual<<<dim3(M), t256, 0, stream>>>(
            X, nullptr, P0, QP, nullptr, nullptr, nullptr, RS, gamma, beta, nullptr, XLNB);
    } else {
        ln_residual<<<dim3(M), t256, 0, stream>>>(
            X, nullptr, P0, VP, nullptr, nullptr, nullptr, RS, gamma, beta, nullptr, XLNB);
    }

    // stage 7: h = gelu(x @ W1 + b1)
    gemm_nt<<<dim3(H / 128, M / 128), t256, 0, stream>>>(
        XLNB, W1T, HB, b1, nullptr, nullptr, D, D, D, H, 0, 0, 0, 0, 3, 0.f);

    // stage 8 + 9
    if (Rs == 4096) {
        // split-K=2: partials to FF / FF2 (no bias; b2 added in LN)
        gemm_nt<<<dim3(D / 128, M / 128, 2), t256, 0, stream>>>(
            HB, W2T, FF, nullptr, nullptr, nullptr, H / 2, H, H, D,
            H / 2, H / 2, (long)(FF2 - FF), 0, 1, 1.0f);
        ln_residual<<<dim3(M), t256, 0, stream>>>(
            nullptr, XLNB, FF, FF2, nullptr, nullptr, b2, nullptr, gamma, beta, out, nullptr);
    } else {
        gemm_nt<<<dim3(D / 128, M / 128), t256, 0, stream>>>(
            HB, W2T, FF, b2, nullptr, nullptr, H, H, H, D, 0, 0, 0, 0, 0, 0.f);
        ln_residual<<<dim3(M), t256, 0, stream>>>(
            nullptr, XLNB, FF, nullptr, nullptr, nullptr, nullptr, nullptr, gamma, beta, out, nullptr);
    }
}

// Round 9
// 595.374 us; speedup vs baseline: 1.0883x; 1.0326x over previous
//
#include <hip/hip_runtime.h>
#include <hip/hip_bf16.h>
#include <stdint.h>

#define AS1 __attribute__((address_space(1)))
#define AS3 __attribute__((address_space(3)))

typedef __bf16 bf16x8 __attribute__((ext_vector_type(8)));
typedef __bf16 bf16x4 __attribute__((ext_vector_type(4)));
typedef float  f32x4  __attribute__((ext_vector_type(4)));

__device__ __forceinline__ void gld_lds16(const void* g, void* l) {
    __builtin_amdgcn_global_load_lds((AS1 void*)g, (AS3 void*)l, 16, 0, 0);
}

// ---------------------------------------------------------------------------
// XCD-aware tile remap (8 XCDs, linear bid & 7). Contiguous C region per XCD.
// ---------------------------------------------------------------------------
__device__ __forceinline__ void xcd_remap(int& bc, int& br) {
    const int GX = gridDim.x, GY = gridDim.y;
    const int L = blockIdx.y * GX + blockIdx.x;
    int rw, rh, nregx;
    if (GX >= 16 && (GX & 1) == 0 && (GY & 3) == 0) {
        rw = GX >> 1; rh = GY >> 2; nregx = 2;       // 2 x 4 regions
    } else if ((GY & 7) == 0) {
        rw = GX;      rh = GY >> 3; nregx = 1;       // 1 x 8 regions
    } else {
        bc = blockIdx.x; br = blockIdx.y; return;
    }
    const int xcd  = L & 7;
    const int slot = L >> 3;
    const int rx = xcd % nregx, ry = xcd / nregx;
    bc = rx * rw + slot % rw;
    br = ry * rh + slot / rw;
}

// ---------------------------------------------------------------------------
// PROVEN engine: NT GEMM 128x128 tile, BK=32, 256 threads, 2x2 waves,
// mfma 16x16x32 bf16, XOR-swizzled LDS, gld_lds16 staging, 4 blocks/CU.
// HISTORY: 256^2 schedules (R1-R3) slower (engine is ~LDS-pipe-bound, not
// MFMA-bound: FF1 LDS demand ~61us/CU vs MFMA 33us); 32x32x16 MFMA rejected
// on paper (inherent 4-way bank conflict in the gld_lds16-forced [row][32]
// layout). PV partials dirtying the full HB span (R6) regressed FF1 writes;
// V^T scatter epilogue (R7) regressed QKV. Keep epilogue stores
// lane-contiguous; partial footprint in XB..VT span <= 32 MiB; every
// dispatch >= 1024 blocks (2/CU runs at ~490 TF vs ~660).
// z-dim: A += z*sA, B += z*sB, C += z*sC, bias += z*sBias (QKV fuse/split-K)
// epilogue: 0 = +bias | 1 = *scale | 3 = +bias, fast GELU |
//           4 = E=exp(v*scale-8) store + per-row fp32 atomic rowsum
//               (softmax fused; normalization folded into LN via rowscale);
//               z=1 redirects C -> Aalt slab and rowsum += sBias (merged
//               two-batch QK^T in one 2048-block dispatch) |
//           6 = dual-slab PV: z=(b<<1)|ks; A = (b ? Aalt : A) + ks*sA,
//               B += b*sB + ks*sA, C += ks*sC + b*sBias; plain store.
// ---------------------------------------------------------------------------
__global__ __launch_bounds__(256, 4)
void gemm_nt(const __bf16* __restrict__ A, const __bf16* __restrict__ B,
             __bf16* __restrict__ C, const float* __restrict__ bias,
             float* __restrict__ rowsum, const __bf16* __restrict__ Aalt,
             int K, int lda, int ldb, int ldc,
             long sA, long sB, long sC, long sBias,
             int ep, float scale)
{
    __shared__ __bf16 smA[2][4096];   // 2 x 128x32
    __shared__ __bf16 smB[2][4096];
    const int t  = threadIdx.x;
    const int l  = t & 63;
    const int w  = t >> 6;
    const int wm = w >> 1, wn = w & 1;
    const int lr = l & 15;
    const int lq = l >> 4;
    const long bz = blockIdx.z;
    int br, bc;
    xcd_remap(bc, br);

    const __bf16* Ae = A;
    long aO, bO, cO;
    if (ep == 6) {
        const long b = bz >> 1, ks = bz & 1;
        Ae = b ? Aalt : A;
        aO = ks * sA;                 // sA = K-offset (elems) per split
        bO = b * sB + ks * sA;
        cO = ks * sC + b * sBias;     // sBias reused as batch-C stride
    } else {
        aO = bz * sA; bO = bz * sB; cO = bz * sC;
    }

    const int swc = ((t & 3) ^ ((t >> 3) & 3)) * 8;
    const __bf16* ag = Ae + aO + (size_t)(br * 128 + (t >> 2)) * lda + swc;
    const __bf16* bg = B  + bO + (size_t)(bc * 128 + (t >> 2)) * ldb + swc;
    const size_t a64 = (size_t)64 * lda, b64 = (size_t)64 * ldb;

    f32x4 acc[4][4];
    const f32x4 zero4 = {0.f, 0.f, 0.f, 0.f};
#pragma unroll
    for (int i = 0; i < 4; ++i)
#pragma unroll
        for (int j = 0; j < 4; ++j) acc[i][j] = zero4;

    const int paOff = (wm * 64 + lr) * 32 + ((lq ^ ((lr >> 1) & 3)) * 8);
    const int pbOff = (wn * 64 + lr) * 32 + ((lq ^ ((lr >> 1) & 3)) * 8);

    auto prefetch = [&](int b) {
        __bf16* la = &smA[b][t * 8];
        __bf16* lb = &smB[b][t * 8];
        gld_lds16(ag,       la);
        gld_lds16(ag + a64, la + 2048);
        gld_lds16(bg,       lb);
        gld_lds16(bg + b64, lb + 2048);
        ag += 32; bg += 32;
    };
    auto compute = [&](int b) {
        const __bf16* pa = &smA[b][paOff];
        const __bf16* pb = &smB[b][pbOff];
        bf16x8 af[4], bfr[4];
#pragma unroll
        for (int i = 0; i < 4; ++i) af[i]  = *(const bf16x8*)(pa + i * 16 * 32);
#pragma unroll
        for (int j = 0; j < 4; ++j) bfr[j] = *(const bf16x8*)(pb + j * 16 * 32);
#pragma unroll
        for (int i = 0; i < 4; ++i)
#pragma unroll
            for (int j = 0; j < 4; ++j)
                acc[i][j] = __builtin_amdgcn_mfma_f32_16x16x32_bf16(af[i], bfr[j], acc[i][j], 0, 0, 0);
    };

    const int nkt = K >> 5;          // always even here
    prefetch(0);
    for (int kt = 0; kt < nkt; kt += 2) {
        __syncthreads();             // tile kt ready; buf1 readers done
        if (kt + 1 < nkt) prefetch(1);
        compute(0);
        __syncthreads();             // tile kt+1 ready; buf0 readers done
        if (kt + 2 < nkt) prefetch(0);
        compute(1);
    }

    // C/D layout (m89-verified): col = lane&15, row = (lane>>4)*4 + reg
    const int r0 = br * 128 + wm * 64 + lq * 4;
    const int c0 = bc * 128 + wn * 64 + lr;
    C += cO;
    const float* bs = bias ? bias + bz * sBias : nullptr;

    if (ep == 4) {
        // fused softmax numerator: E = exp(v*scale - 8); constant shift
        // cancels exactly at normalization (scores bounded, no row max
        // needed). fp32 row sums via 16-lane shfl_xor reduce + one
        // atomicAdd per row per wave. z=1: write alt slab, offset rowsum.
        __bf16* Ce = (bz ? (__bf16*)Aalt : C);
        float*  rsum = rowsum + bz * sBias;
#pragma unroll
        for (int i = 0; i < 4; ++i) {
            float rs4[4] = {0.f, 0.f, 0.f, 0.f};
#pragma unroll
            for (int j = 0; j < 4; ++j) {
                const int col = c0 + j * 16;
#pragma unroll
                for (int r = 0; r < 4; ++r) {
                    const long row = r0 + i * 16 + r;
                    const float e = __expf(acc[i][j][r] * scale - 8.0f);
                    Ce[row * (long)ldc + col] = (__bf16)e;
                    rs4[r] += e;
                }
            }
#pragma unroll
            for (int r = 0; r < 4; ++r) {
                float s = rs4[r];
                s += __shfl_xor(s, 1, 64);
                s += __shfl_xor(s, 2, 64);
                s += __shfl_xor(s, 4, 64);
                s += __shfl_xor(s, 8, 64);
                if (lr == 0) atomicAdd(&rsum[r0 + i * 16 + r], s);
            }
        }
        return;
    }

#pragma unroll
    for (int i = 0; i < 4; ++i) {
#pragma unroll
        for (int j = 0; j < 4; ++j) {
            const int col = c0 + j * 16;
            const float bcol = (ep == 0 && bs) ? bs[col] : (ep == 3 && bs) ? bs[col] : 0.f;
#pragma unroll
            for (int r = 0; r < 4; ++r) {
                const long row = r0 + i * 16 + r;
                const long idx = row * (long)ldc + col;
                const float v = acc[i][j][r];
                if (ep == 0 || ep == 6) {
                    C[idx] = (__bf16)(v + bcol);
                } else if (ep == 1) {
                    C[idx] = (__bf16)(v * scale);
                } else {
                    const float u = v + bcol;
                    const float z = 1.59576912f * (u + 0.044715f * u * u * u);
                    C[idx] = (__bf16)(u / (1.f + __expf(-z)));
                }
            }
        }
    }
}

// ---------------------------------------------------------------------------
__global__ __launch_bounds__(256)
void conv_bf16(const float* __restrict__ in, __bf16* __restrict__ out)
{
    const long i = (long)blockIdx.x * 256 + threadIdx.x;
    const float4 f = ((const float4*)in)[i];
    bf16x4 o = {(__bf16)f.x, (__bf16)f.y, (__bf16)f.z, (__bf16)f.w};
    ((bf16x4*)out)[i] = o;
}

// ---------------------------------------------------------------------------
// f32 [K,N] -> bf16 [N,K] transpose.
// ---------------------------------------------------------------------------
__global__ void tr_f32_bf16(const float* __restrict__ in, __bf16* __restrict__ out,
                            int K, int N)
{
    __shared__ float tl[32][33];
    const int x = threadIdx.x, y = threadIdx.y;
    const int n0 = blockIdx.x * 32, k0 = blockIdx.y * 32;
#pragma unroll
    for (int i = 0; i < 4; ++i)
        tl[y + 8 * i][x] = in[(size_t)(k0 + y + 8 * i) * N + n0 + x];
    __syncthreads();
#pragma unroll
    for (int i = 0; i < 4; ++i)
        out[(size_t)(n0 + y + 8 * i) * K + k0 + x] = (__bf16)tl[x][y + 8 * i];
}

// ---------------------------------------------------------------------------
// Three square f32 [D,D] -> bf16 [D,D] transposes in one dispatch (z picks
// the input pointer explicitly — no cross-allocation strides).
// ---------------------------------------------------------------------------
__global__ void tr3_f32_bf16(const float* __restrict__ in0,
                             const float* __restrict__ in1,
                             const float* __restrict__ in2,
                             __bf16* __restrict__ out, int D)
{
    const float* in = (blockIdx.z == 0) ? in0 : (blockIdx.z == 1) ? in1 : in2;
    out += (size_t)blockIdx.z * D * D;
    __shared__ float tl[32][33];
    const int x = threadIdx.x, y = threadIdx.y;
    const int n0 = blockIdx.x * 32, k0 = blockIdx.y * 32;
#pragma unroll
    for (int i = 0; i < 4; ++i)
        tl[y + 8 * i][x] = in[(size_t)(k0 + y + 8 * i) * D + n0 + x];
    __syncthreads();
#pragma unroll
    for (int i = 0; i < 4; ++i)
        out[(size_t)(n0 + y + 8 * i) * D + k0 + x] = (__bf16)tl[x][y + 8 * i];
}

// ---------------------------------------------------------------------------
__global__ void tr_bf16(const __bf16* __restrict__ in, __bf16* __restrict__ out,
                        int R, int C)
{
    in  += (size_t)blockIdx.z * R * C;
    out += (size_t)blockIdx.z * R * C;
    __shared__ __bf16 tl[32][33];
    const int x = threadIdx.x, y = threadIdx.y;
    const int c0 = blockIdx.x * 32, r0 = blockIdx.y * 32;
#pragma unroll
    for (int i = 0; i < 4; ++i)
        tl[y + 8 * i][x] = in[(size_t)(r0 + y + 8 * i) * C + c0 + x];
    __syncthreads();
#pragma unroll
    for (int i = 0; i < 4; ++i)
        out[(size_t)(c0 + y + 8 * i) * R + r0 + x] = tl[x][y + 8 * i];
}

// ---------------------------------------------------------------------------
// y = LayerNorm(a + P [+ lnb_col]) * gamma + beta ; row = 1024
// P = (b [+ b2 + b3 + b4]) * (1/rowscale[row] if rowscale)  -- softmax fold
// ---------------------------------------------------------------------------
__global__ __launch_bounds__(256)
void ln_residual(const float* __restrict__ af, const __bf16* __restrict__ ab,
                 const __bf16* __restrict__ bb, const __bf16* __restrict__ bb2,
                 const __bf16* __restrict__ bb3, const __bf16* __restrict__ bb4,
                 const float* __restrict__ lnb,
                 const float* __restrict__ rowscale,
                 const float* __restrict__ gamma, const float* __restrict__ beta,
                 float* __restrict__ outf, __bf16* __restrict__ outb)
{
    const long row = blockIdx.x;
    const int t = threadIdx.x;
    float x0, x1, x2, x3;
    if (af) {
        const float4 va = ((const float4*)(af + row * 1024))[t];
        x0 = va.x; x1 = va.y; x2 = va.z; x3 = va.w;
    } else {
        const bf16x4 va = ((const bf16x4*)(ab + row * 1024))[t];
        x0 = (float)va[0]; x1 = (float)va[1]; x2 = (float)va[2]; x3 = (float)va[3];
    }
    float p0, p1, p2, p3;
    {
        const bf16x4 vb = ((const bf16x4*)(bb + row * 1024))[t];
        p0 = (float)vb[0]; p1 = (float)vb[1]; p2 = (float)vb[2]; p3 = (float)vb[3];
    }
    if (bb2) {
        const bf16x4 vb = ((const bf16x4*)(bb2 + row * 1024))[t];
        p0 += (float)vb[0]; p1 += (float)vb[1]; p2 += (float)vb[2]; p3 += (float)vb[3];
    }
    if (bb3) {
        const bf16x4 vb = ((const bf16x4*)(bb3 + row * 1024))[t];
        p0 += (float)vb[0]; p1 += (float)vb[1]; p2 += (float)vb[2]; p3 += (float)vb[3];
    }
    if (bb4) {
        const bf16x4 vb = ((const bf16x4*)(bb4 + row * 1024))[t];
        p0 += (float)vb[0]; p1 += (float)vb[1]; p2 += (float)vb[2]; p3 += (float)vb[3];
    }
    if (rowscale) {
        const float inv = 1.f / rowscale[row];
        p0 *= inv; p1 *= inv; p2 *= inv; p3 *= inv;
    }
    x0 += p0; x1 += p1; x2 += p2; x3 += p3;
    if (lnb) {
        const float4 vb = ((const float4*)lnb)[t];
        x0 += vb.x; x1 += vb.y; x2 += vb.z; x3 += vb.w;
    }
    float s = x0 + x1 + x2 + x3;
    float q = x0 * x0 + x1 * x1 + x2 * x2 + x3 * x3;
#pragma unroll
    for (int o = 32; o; o >>= 1) { s += __shfl_down(s, o, 64); q += __shfl_down(q, o, 64); }
    __shared__ float rs[4], rq[4];
    if ((t & 63) == 0) { rs[t >> 6] = s; rq[t >> 6] = q; }
    __syncthreads();
    s = rs[0] + rs[1] + rs[2] + rs[3];
    q = rq[0] + rq[1] + rq[2] + rq[3];
    const float mu  = s * (1.f / 1024.f);
    const float inv = rsqrtf(q * (1.f / 1024.f) - mu * mu + 1e-5f);
    const float4 g  = ((const float4*)gamma)[t];
    const float4 be = ((const float4*)beta)[t];
    const float y0 = (x0 - mu) * inv * g.x + be.x;
    const float y1 = (x1 - mu) * inv * g.y + be.y;
    const float y2 = (x2 - mu) * inv * g.z + be.z;
    const float y3 = (x3 - mu) * inv * g.w + be.w;
    if (outf) ((float4*)(outf + row * 1024))[t] = make_float4(y0, y1, y2, y3);
    if (outb) {
        bf16x4 o4 = {(__bf16)y0, (__bf16)y1, (__bf16)y2, (__bf16)y3};
        ((bf16x4*)outb)[row * 256 + t] = o4;
    }
}

// diagnostic / fill: out[i] = v  (also used to zero the rowsum array)
__global__ __launch_bounds__(256)
void fill_diag(float* __restrict__ out, float v, long n)
{
    const long i = (long)blockIdx.x * 256 + threadIdx.x;
    if (i < n) out[i] = v;
}

// ---------------------------------------------------------------------------
extern "C" void kernel_launch(void* const* d_in, const int* in_sizes, int n_in,
                              void* d_out, int out_size, void* d_ws, size_t ws_size,
                              hipStream_t stream)
{
    const float* X  = (const float*)d_in[0];
    const float* Wq = (const float*)d_in[1];
    const float* bq = (const float*)d_in[2];
    const float* Wk = (const float*)d_in[3];
    const float* bk = (const float*)d_in[4];
    const float* Wv = (const float*)d_in[5];
    const float* bv = (const float*)d_in[6];
    const float* W1 = (const float*)d_in[7];
    const float* b1 = (const float*)d_in[8];
    const float* W2 = (const float*)d_in[9];
    const float* b2 = (const float*)d_in[10];
    const float* gamma = (const float*)d_in[11];
    const float* beta  = (const float*)d_in[12];
    float* out = (float*)d_out;

    const int S = 4096, D = 1024, H = 4096;
    const int M = 2 * S;
    const size_t MB = 1ull << 20;

    // ---- workspace layout (128 MiB tier1 / 112 MiB tier2) ----
    // 0:W1T(8) 8:W2T(8) 16:XB/P0 32:QP/P1 48:KP 64:VP(->RS tier1) 80:VT->FF
    // 16..80: HB (64 MiB, after LN6)  96: WQT -> SL0 -> XLNB  112: FF2
    // Tier1 attention: SL0 = ws+96 (batch 0 scores), SL1 = d_out (batch 1
    // scores; 32 MiB exact). QK^T runs ONCE (z=2, 2048 blocks); PV runs ONCE
    // (z=4 batch x splitK, 1024 blocks). Partials -> P0(XB) + QP. Dirty HB
    // span = 32 MiB (R6 lesson). RS -> VP base (dead after tr_bf16).
    char* ws = (char*)d_ws;
    __bf16* W1T = (__bf16*)(ws);
    __bf16* W2T = (__bf16*)(ws + 8 * MB);
    __bf16* XB  = (__bf16*)(ws + 16 * MB);
    __bf16* P0  = XB;
    __bf16* QP  = (__bf16*)(ws + 32 * MB);
    __bf16* KP  = (__bf16*)(ws + 48 * MB);
    __bf16* VP  = (__bf16*)(ws + 64 * MB);
    __bf16* VT  = (__bf16*)(ws + 80 * MB);
    __bf16* FF  = VT;
    __bf16* HB  = XB;                        // 64 MiB span, used post-LN6
    __bf16* SL0 = (__bf16*)(ws + 96 * MB);
    __bf16* WQT = (__bf16*)(ws + 96 * MB);
    float*  BIAS= (float*)(ws + 96 * MB + 6 * MB);
    __bf16* XLNB= (__bf16*)(ws + 96 * MB);
    __bf16* FF2 = (__bf16*)(ws + 112 * MB);
    __bf16* SL1 = (__bf16*)out;              // 32 MiB scratch slab (tier1)

    int Rs;
    if (ws_size >= 128 * MB)      Rs = 4096;
    else if (ws_size >= 112 * MB) Rs = 2048;
    else {
        fill_diag<<<dim3((out_size + 255) / 256), dim3(256), 0, stream>>>(
            out, (float)(ws_size >> 20), out_size);
        return;
    }
    float* RS = (Rs == 4096) ? (float*)VP : out;  // tier2 keeps RS in d_out

    const dim3 t256(256);
    const dim3 t32x8(32, 8);

    // stage 0: dtype prep
    conv_bf16<<<dim3(M * D / 1024), t256, 0, stream>>>(X, XB);
    tr3_f32_bf16<<<dim3(D / 32, D / 32, 3), t32x8, 0, stream>>>(Wq, Wk, Wv, WQT, D);
    tr_f32_bf16<<<dim3(H / 32, D / 32), t32x8, 0, stream>>>(W1, W1T, D, H);
    tr_f32_bf16<<<dim3(D / 32, H / 32), t32x8, 0, stream>>>(W2, W2T, H, D);
    hipMemcpyAsync(BIAS,         bq, D * 4, hipMemcpyDeviceToDevice, stream);
    hipMemcpyAsync(BIAS + D,     bk, D * 4, hipMemcpyDeviceToDevice, stream);
    hipMemcpyAsync(BIAS + 2 * D, bv, D * 4, hipMemcpyDeviceToDevice, stream);

    // stage 1: fused QKV projections, z = {q,k,v} -> QP/KP/VP
    gemm_nt<<<dim3(D / 128, M / 128, 3), t256, 0, stream>>>(
        XB, WQT, QP, BIAS, nullptr, nullptr, D, D, D, D,
        0, (long)D * D, (long)M * D, D, 0, 0.f);

    // stage 2: V^T per batch [D,S]
    tr_bf16<<<dim3(D / 32, S / 32, 2), t32x8, 0, stream>>>(VP, VT, S, D);

    // zero fused-softmax row sums (VP dead after transpose / d_out tier2)
    fill_diag<<<dim3(M / 256), t256, 0, stream>>>(RS, 0.f, M);

    // stages 3-5: attention (quirk: queries<-KP, keys<-QP); QK^T ep=4 fuses
    // exp + rowsum (softmax pass eliminated; normalization folded into LN6).
    if (Rs == 4096) {
        // merged QK^T, both batches in one 2048-block dispatch:
        // z=0 -> SL0, z=1 -> SL1 (d_out) + rowsum offset S
        gemm_nt<<<dim3(S / 128, S / 128, 2), t256, 0, stream>>>(
            KP, QP, SL0, nullptr, RS, SL1,
            D, D, D, S, (long)S * D, (long)S * D, 0, (long)S, 4, 0.03125f);
        // PV combined, ep=6: z=(b<<1)|ks -> 1024 blocks (4/CU).
        // A = SL0/SL1 + ks*2048; B = VT + b*DS + ks*2048; C = P_ks + b*SD.
        gemm_nt<<<dim3(D / 128, S / 128, 4), t256, 0, stream>>>(
            SL0, VT, P0, nullptr, nullptr, SL1,
            S / 2, S, S, D,
            (long)(S / 2), (long)D * S, (long)(QP - P0), (long)S * D,
            6, 0.f);
    } else {
        // tier2 fallback: per-chunk QK -> SL0 (16 MiB slab), PV split-K=2
        // partials -> P0 / VP (RS lives in d_out here).
        const long sCpv = (long)(VP - P0);
        for (int b = 0; b < 2; ++b) {
            for (int c = 0; c < S / Rs; ++c) {
                const __bf16* Ak = KP + (size_t)(b * S + c * Rs) * D;
                gemm_nt<<<dim3(S / 128, Rs / 128), t256, 0, stream>>>(
                    Ak, QP + (size_t)b * S * D, SL0, nullptr,
                    RS + (size_t)b * S + c * Rs, nullptr,
                    D, D, D, S, 0, 0, 0, 0, 4, 0.03125f);
                gemm_nt<<<dim3(D / 128, Rs / 128, 2), t256, 0, stream>>>(
                    SL0, VT + (size_t)b * D * S, P0 + (size_t)(b * S + c * Rs) * D,
                    nullptr, nullptr, nullptr,
                    S / 2, S, S, D, S / 2, S / 2, sCpv, 0, 0, 0.f);
            }
        }
    }

    // stage 6: x = LN(input + (P0 + P1)/rowsum) -> bf16
    if (Rs == 4096) {
        ln_residual<<<dim3(M), t256, 0, stream>>>(
            X, nullptr, P0, QP, nullptr, nullptr, nullptr, RS, gamma, beta, nullptr, XLNB);
    } else {
        ln_residual<<<dim3(M), t256, 0, stream>>>(
            X, nullptr, P0, VP, nullptr, nullptr, nullptr, RS, gamma, beta, nullptr, XLNB);
    }

    // stage 7: h = gelu(x @ W1 + b1)
    gemm_nt<<<dim3(H / 128, M / 128), t256, 0, stream>>>(
        XLNB, W1T, HB, b1, nullptr, nullptr, D, D, D, H, 0, 0, 0, 0, 3, 0.f);

    // stage 8 + 9
    if (Rs == 4096) {
        // split-K=2: partials to FF / FF2 (no bias; b2 added in LN)
        gemm_nt<<<dim3(D / 128, M / 128, 2), t256, 0, stream>>>(
            HB, W2T, FF, nullptr, nullptr, nullptr, H / 2, H, H, D,
            H / 2, H / 2, (long)(FF2 - FF), 0, 1, 1.0f);
        ln_residual<<<dim3(M), t256, 0, stream>>>(
            nullptr, XLNB, FF, FF2, nullptr, nullptr, b2, nullptr, gamma, beta, out, nullptr);
    } else {
        gemm_nt<<<dim3(D / 128, M / 128), t256, 0, stream>>>(
            HB, W2T, FF, b2, nullptr, nullptr, H, H, H, D, 0, 0, 0, 0, 0, 0.f);
        ln_residual<<<dim3(M), t256, 0, stream>>>(
            nullptr, XLNB, FF, nullptr, nullptr, nullptr, nullptr, nullptr, gamma, beta, out, nullptr);
    }
}

// Round 11
// 592.393 us; speedup vs baseline: 1.0938x; 1.0050x over previous
//
#include <hip/hip_runtime.h>
#include <hip/hip_bf16.h>
#include <stdint.h>

#define AS1 __attribute__((address_space(1)))
#define AS3 __attribute__((address_space(3)))

typedef __bf16 bf16x8 __attribute__((ext_vector_type(8)));
typedef __bf16 bf16x4 __attribute__((ext_vector_type(4)));
typedef float  f32x4  __attribute__((ext_vector_type(4)));

__device__ __forceinline__ void gld_lds16(const void* g, void* l) {
    __builtin_amdgcn_global_load_lds((AS1 void*)g, (AS3 void*)l, 16, 0, 0);
}

// ---------------------------------------------------------------------------
// XCD-aware tile remap (8 XCDs, linear bid & 7). Contiguous C region per XCD.
// ---------------------------------------------------------------------------
__device__ __forceinline__ void xcd_remap(int& bc, int& br) {
    const int GX = gridDim.x, GY = gridDim.y;
    const int L = blockIdx.y * GX + blockIdx.x;
    int rw, rh, nregx;
    if (GX >= 16 && (GX & 1) == 0 && (GY & 3) == 0) {
        rw = GX >> 1; rh = GY >> 2; nregx = 2;       // 2 x 4 regions
    } else if ((GY & 7) == 0) {
        rw = GX;      rh = GY >> 3; nregx = 1;       // 1 x 8 regions
    } else {
        bc = blockIdx.x; br = blockIdx.y; return;
    }
    const int xcd  = L & 7;
    const int slot = L >> 3;
    const int rx = xcd % nregx, ry = xcd / nregx;
    bc = rx * rw + slot % rw;
    br = ry * rh + slot / rw;
}

// ---------------------------------------------------------------------------
// PROVEN engine: NT GEMM 128x128 tile, BK=32, 256 threads, 2x2 waves,
// mfma 16x16x32 bf16, XOR-swizzled LDS, gld_lds16 staging, 4 blocks/CU.
// HISTORY: 256^2 schedules (R1-R3) slower (engine ~LDS-pipe-bound, not
// MFMA-bound); 32x32x16 MFMA rejected (inherent 4-way bank conflict in the
// gld_lds16-forced [row][32] layout); 256x128 tile rejected (acc regs ->
// spill at 3 blocks/CU). PV partials dirtying the full HB span (R6)
// regressed FF1 writes; V^T scatter epilogue (R7) regressed QKV. R10: RS in
// ws+112 was clobbered by SL0 (96..128) -> NaN; RS must live at VP and be
// zeroed AFTER tr_bf16 (VP is the transpose source). Keep epilogue stores
// lane-contiguous; partial footprint in XB..VT <= 32 MiB; every dispatch
// >= 1024 blocks (2/CU runs at ~490 TF vs ~660).
// z-dim: A += z*sA, B += z*sB, C += z*sC, bias += z*sBias (QKV fuse/split-K)
// epilogue: 0 = +bias | 1 = *scale | 3 = +bias, fast GELU |
//           4 = E=exp(v*scale-8) store + per-row fp32 atomic rowsum
//               (softmax fused; normalization folded into LN via rowscale);
//               z=1 redirects C -> Aalt slab and rowsum += sBias (merged
//               two-batch QK^T in one 2048-block dispatch) |
//           6 = dual-slab PV: z=(b<<1)|ks; A = (b ? Aalt : A) + ks*sA,
//               B += b*sB + ks*sA, C += ks*sC + b*sBias; plain store.
// ---------------------------------------------------------------------------
__global__ __launch_bounds__(256, 4)
void gemm_nt(const __bf16* __restrict__ A, const __bf16* __restrict__ B,
             __bf16* __restrict__ C, const float* __restrict__ bias,
             float* __restrict__ rowsum, const __bf16* __restrict__ Aalt,
             int K, int lda, int ldb, int ldc,
             long sA, long sB, long sC, long sBias,
             int ep, float scale)
{
    __shared__ __bf16 smA[2][4096];   // 2 x 128x32
    __shared__ __bf16 smB[2][4096];
    const int t  = threadIdx.x;
    const int l  = t & 63;
    const int w  = t >> 6;
    const int wm = w >> 1, wn = w & 1;
    const int lr = l & 15;
    const int lq = l >> 4;
    const long bz = blockIdx.z;
    int br, bc;
    xcd_remap(bc, br);

    const __bf16* Ae = A;
    long aO, bO, cO;
    if (ep == 6) {
        const long b = bz >> 1, ks = bz & 1;
        Ae = b ? Aalt : A;
        aO = ks * sA;                 // sA = K-offset (elems) per split
        bO = b * sB + ks * sA;
        cO = ks * sC + b * sBias;     // sBias reused as batch-C stride
    } else {
        aO = bz * sA; bO = bz * sB; cO = bz * sC;
    }

    const int swc = ((t & 3) ^ ((t >> 3) & 3)) * 8;
    const __bf16* ag = Ae + aO + (size_t)(br * 128 + (t >> 2)) * lda + swc;
    const __bf16* bg = B  + bO + (size_t)(bc * 128 + (t >> 2)) * ldb + swc;
    const size_t a64 = (size_t)64 * lda, b64 = (size_t)64 * ldb;

    f32x4 acc[4][4];
    const f32x4 zero4 = {0.f, 0.f, 0.f, 0.f};
#pragma unroll
    for (int i = 0; i < 4; ++i)
#pragma unroll
        for (int j = 0; j < 4; ++j) acc[i][j] = zero4;

    const int paOff = (wm * 64 + lr) * 32 + ((lq ^ ((lr >> 1) & 3)) * 8);
    const int pbOff = (wn * 64 + lr) * 32 + ((lq ^ ((lr >> 1) & 3)) * 8);

    auto prefetch = [&](int b) {
        __bf16* la = &smA[b][t * 8];
        __bf16* lb = &smB[b][t * 8];
        gld_lds16(ag,       la);
        gld_lds16(ag + a64, la + 2048);
        gld_lds16(bg,       lb);
        gld_lds16(bg + b64, lb + 2048);
        ag += 32; bg += 32;
    };
    auto compute = [&](int b) {
        const __bf16* pa = &smA[b][paOff];
        const __bf16* pb = &smB[b][pbOff];
        bf16x8 af[4], bfr[4];
#pragma unroll
        for (int i = 0; i < 4; ++i) af[i]  = *(const bf16x8*)(pa + i * 16 * 32);
#pragma unroll
        for (int j = 0; j < 4; ++j) bfr[j] = *(const bf16x8*)(pb + j * 16 * 32);
#pragma unroll
        for (int i = 0; i < 4; ++i)
#pragma unroll
            for (int j = 0; j < 4; ++j)
                acc[i][j] = __builtin_amdgcn_mfma_f32_16x16x32_bf16(af[i], bfr[j], acc[i][j], 0, 0, 0);
    };

    const int nkt = K >> 5;          // always even here
    prefetch(0);
    for (int kt = 0; kt < nkt; kt += 2) {
        __syncthreads();             // tile kt ready; buf1 readers done
        if (kt + 1 < nkt) prefetch(1);
        compute(0);
        __syncthreads();             // tile kt+1 ready; buf0 readers done
        if (kt + 2 < nkt) prefetch(0);
        compute(1);
    }

    // C/D layout (m89-verified): col = lane&15, row = (lane>>4)*4 + reg
    const int r0 = br * 128 + wm * 64 + lq * 4;
    const int c0 = bc * 128 + wn * 64 + lr;
    C += cO;
    const float* bs = bias ? bias + bz * sBias : nullptr;

    if (ep == 4) {
        // fused softmax numerator: E = exp(v*scale - 8); constant shift
        // cancels exactly at normalization (scores bounded, no row max
        // needed). fp32 row sums via 16-lane shfl_xor reduce + one
        // atomicAdd per row per wave. z=1: write alt slab, offset rowsum.
        __bf16* Ce = (bz ? (__bf16*)Aalt : C);
        float*  rsum = rowsum + bz * sBias;
#pragma unroll
        for (int i = 0; i < 4; ++i) {
            float rs4[4] = {0.f, 0.f, 0.f, 0.f};
#pragma unroll
            for (int j = 0; j < 4; ++j) {
                const int col = c0 + j * 16;
#pragma unroll
                for (int r = 0; r < 4; ++r) {
                    const long row = r0 + i * 16 + r;
                    const float e = __expf(acc[i][j][r] * scale - 8.0f);
                    Ce[row * (long)ldc + col] = (__bf16)e;
                    rs4[r] += e;
                }
            }
#pragma unroll
            for (int r = 0; r < 4; ++r) {
                float s = rs4[r];
                s += __shfl_xor(s, 1, 64);
                s += __shfl_xor(s, 2, 64);
                s += __shfl_xor(s, 4, 64);
                s += __shfl_xor(s, 8, 64);
                if (lr == 0) atomicAdd(&rsum[r0 + i * 16 + r], s);
            }
        }
        return;
    }

#pragma unroll
    for (int i = 0; i < 4; ++i) {
#pragma unroll
        for (int j = 0; j < 4; ++j) {
            const int col = c0 + j * 16;
            const float bcol = (ep == 0 && bs) ? bs[col] : (ep == 3 && bs) ? bs[col] : 0.f;
#pragma unroll
            for (int r = 0; r < 4; ++r) {
                const long row = r0 + i * 16 + r;
                const long idx = row * (long)ldc + col;
                const float v = acc[i][j][r];
                if (ep == 0 || ep == 6) {
                    C[idx] = (__bf16)(v + bcol);
                } else if (ep == 1) {
                    C[idx] = (__bf16)(v * scale);
                } else {
                    const float u = v + bcol;
                    const float z = 1.59576912f * (u + 0.044715f * u * u * u);
                    C[idx] = (__bf16)(u / (1.f + __expf(-z)));
                }
            }
        }
    }
}

// ---------------------------------------------------------------------------
// MEGA-PREP: one dispatch replaces conv_bf16 + 3x weight transposes (QKV) +
// W1/W2 transposes + bias packing. 1D grid, range-decoded segments; all
// 256-thread blocks (transposes decode x=t&31, y=t>>5).
// Segments (block ranges):
//   [0, 8192)                conv: X fp32 -> XB bf16 (float4/thread)
//   [8192, 8193)             bias pack bq|bk|bv -> BIAS
//   [8193, 8193+3072)        Wq/Wk/Wv [D,D] -> WQT (z = r/1024)
//   [+3072, +3072+4096)      W1 [D,H] -> W1T
//   [+7168, +7168+4096)      W2 [H,D] -> W2T
// NOTE: RS zeroing must NOT live here (R10 lesson: RS sits at VP, whose
// contents are produced by QKV and consumed by tr_bf16 after prep).
// ---------------------------------------------------------------------------
__global__ __launch_bounds__(256)
void prep(const float* __restrict__ X, __bf16* __restrict__ XB,
          const float* __restrict__ Wq, const float* __restrict__ Wk,
          const float* __restrict__ Wv, __bf16* __restrict__ WQT,
          const float* __restrict__ W1, __bf16* __restrict__ W1T,
          const float* __restrict__ W2, __bf16* __restrict__ W2T,
          const float* __restrict__ bq, const float* __restrict__ bk,
          const float* __restrict__ bv, float* __restrict__ BIAS)
{
    int b = blockIdx.x;
    const int t = threadIdx.x;

    if (b < 8192) {                       // conv segment
        const long i = (long)b * 256 + t;
        const float4 f = ((const float4*)X)[i];
        bf16x4 o = {(__bf16)f.x, (__bf16)f.y, (__bf16)f.z, (__bf16)f.w};
        ((bf16x4*)XB)[i] = o;
        return;
    }
    b -= 8192;
    if (b < 1) {                          // bias pack
        ((float4*)BIAS)[t]       = ((const float4*)bq)[t];
        ((float4*)BIAS)[256 + t] = ((const float4*)bk)[t];
        ((float4*)BIAS)[512 + t] = ((const float4*)bv)[t];
        return;
    }
    b -= 1;

    // transpose segments: f32 [K,N] -> bf16 [N,K], 32x32 tiles
    const int x = t & 31, y = t >> 5;
    __shared__ float tl[32][33];
    const float* in; __bf16* outp; int K, N, bx, by;
    if (b < 3072) {
        const int z = b / 1024, r = b % 1024;
        in = (z == 0) ? Wq : (z == 1) ? Wk : Wv;
        outp = WQT + (size_t)z * 1024 * 1024;
        K = 1024; N = 1024; bx = r & 31; by = r >> 5;
    } else if (b < 3072 + 4096) {
        const int r = b - 3072;
        in = W1; outp = W1T; K = 1024; N = 4096;
        bx = r & 127; by = r >> 7;        // grid (N/32=128, K/32=32)
    } else {
        const int r = b - 3072 - 4096;
        in = W2; outp = W2T; K = 4096; N = 1024;
        bx = r & 31; by = r >> 5;         // grid (N/32=32, K/32=128)
    }
    const int n0 = bx * 32, k0 = by * 32;
#pragma unroll
    for (int i = 0; i < 4; ++i)
        tl[y + 8 * i][x] = in[(size_t)(k0 + y + 8 * i) * N + n0 + x];
    __syncthreads();
#pragma unroll
    for (int i = 0; i < 4; ++i)
        outp[(size_t)(n0 + y + 8 * i) * K + k0 + x] = (__bf16)tl[x][y + 8 * i];
}

// ---------------------------------------------------------------------------
__global__ void tr_bf16(const __bf16* __restrict__ in, __bf16* __restrict__ out,
                        int R, int C)
{
    in  += (size_t)blockIdx.z * R * C;
    out += (size_t)blockIdx.z * R * C;
    __shared__ __bf16 tl[32][33];
    const int x = threadIdx.x, y = threadIdx.y;
    const int c0 = blockIdx.x * 32, r0 = blockIdx.y * 32;
#pragma unroll
    for (int i = 0; i < 4; ++i)
        tl[y + 8 * i][x] = in[(size_t)(r0 + y + 8 * i) * C + c0 + x];
    __syncthreads();
#pragma unroll
    for (int i = 0; i < 4; ++i)
        out[(size_t)(c0 + y + 8 * i) * R + r0 + x] = tl[x][y + 8 * i];
}

// ---------------------------------------------------------------------------
// y = LayerNorm(a + P [+ lnb_col]) * gamma + beta ; row = 1024
// P = (b [+ b2]) * (1/rowscale[row] if rowscale)  -- softmax fold
// ---------------------------------------------------------------------------
__global__ __launch_bounds__(256)
void ln_residual(const float* __restrict__ af, const __bf16* __restrict__ ab,
                 const __bf16* __restrict__ bb, const __bf16* __restrict__ bb2,
                 const float* __restrict__ lnb,
                 const float* __restrict__ rowscale,
                 const float* __restrict__ gamma, const float* __restrict__ beta,
                 float* __restrict__ outf, __bf16* __restrict__ outb)
{
    const long row = blockIdx.x;
    const int t = threadIdx.x;
    float x0, x1, x2, x3;
    if (af) {
        const float4 va = ((const float4*)(af + row * 1024))[t];
        x0 = va.x; x1 = va.y; x2 = va.z; x3 = va.w;
    } else {
        const bf16x4 va = ((const bf16x4*)(ab + row * 1024))[t];
        x0 = (float)va[0]; x1 = (float)va[1]; x2 = (float)va[2]; x3 = (float)va[3];
    }
    float p0, p1, p2, p3;
    {
        const bf16x4 vb = ((const bf16x4*)(bb + row * 1024))[t];
        p0 = (float)vb[0]; p1 = (float)vb[1]; p2 = (float)vb[2]; p3 = (float)vb[3];
    }
    if (bb2) {
        const bf16x4 vb = ((const bf16x4*)(bb2 + row * 1024))[t];
        p0 += (float)vb[0]; p1 += (float)vb[1]; p2 += (float)vb[2]; p3 += (float)vb[3];
    }
    if (rowscale) {
        const float inv = 1.f / rowscale[row];
        p0 *= inv; p1 *= inv; p2 *= inv; p3 *= inv;
    }
    x0 += p0; x1 += p1; x2 += p2; x3 += p3;
    if (lnb) {
        const float4 vb = ((const float4*)lnb)[t];
        x0 += vb.x; x1 += vb.y; x2 += vb.z; x3 += vb.w;
    }
    float s = x0 + x1 + x2 + x3;
    float q = x0 * x0 + x1 * x1 + x2 * x2 + x3 * x3;
#pragma unroll
    for (int o = 32; o; o >>= 1) { s += __shfl_down(s, o, 64); q += __shfl_down(q, o, 64); }
    __shared__ float rs[4], rq[4];
    if ((t & 63) == 0) { rs[t >> 6] = s; rq[t >> 6] = q; }
    __syncthreads();
    s = rs[0] + rs[1] + rs[2] + rs[3];
    q = rq[0] + rq[1] + rq[2] + rq[3];
    const float mu  = s * (1.f / 1024.f);
    const float inv = rsqrtf(q * (1.f / 1024.f) - mu * mu + 1e-5f);
    const float4 g  = ((const float4*)gamma)[t];
    const float4 be = ((const float4*)beta)[t];
    const float y0 = (x0 - mu) * inv * g.x + be.x;
    const float y1 = (x1 - mu) * inv * g.y + be.y;
    const float y2 = (x2 - mu) * inv * g.z + be.z;
    const float y3 = (x3 - mu) * inv * g.w + be.w;
    if (outf) ((float4*)(outf + row * 1024))[t] = make_float4(y0, y1, y2, y3);
    if (outb) {
        bf16x4 o4 = {(__bf16)y0, (__bf16)y1, (__bf16)y2, (__bf16)y3};
        ((bf16x4*)outb)[row * 256 + t] = o4;
    }
}

// diagnostic / fill: out[i] = v  (also used to zero the rowsum array)
__global__ __launch_bounds__(256)
void fill_diag(float* __restrict__ out, float v, long n)
{
    const long i = (long)blockIdx.x * 256 + threadIdx.x;
    if (i < n) out[i] = v;
}

// ---------------------------------------------------------------------------
extern "C" void kernel_launch(void* const* d_in, const int* in_sizes, int n_in,
                              void* d_out, int out_size, void* d_ws, size_t ws_size,
                              hipStream_t stream)
{
    const float* X  = (const float*)d_in[0];
    const float* Wq = (const float*)d_in[1];
    const float* bq = (const float*)d_in[2];
    const float* Wk = (const float*)d_in[3];
    const float* bk = (const float*)d_in[4];
    const float* Wv = (const float*)d_in[5];
    const float* bv = (const float*)d_in[6];
    const float* W1 = (const float*)d_in[7];
    const float* b1 = (const float*)d_in[8];
    const float* W2 = (const float*)d_in[9];
    const float* b2 = (const float*)d_in[10];
    const float* gamma = (const float*)d_in[11];
    const float* beta  = (const float*)d_in[12];
    float* out = (float*)d_out;

    const int S = 4096, D = 1024, H = 4096;
    const int M = 2 * S;
    const size_t MB = 1ull << 20;

    // ---- workspace layout (128 MiB tier1 / 112 MiB tier2) ----
    // 0:W1T(8) 8:W2T(8) 16:XB/P0 32:QP/P1 48:KP 64:VP(->RS) 80:VT->FF
    // 16..80: HB (64 MiB, after LN6)  96: WQT+BIAS -> SL0 -> XLNB  112: FF2
    // Tier1: SL0 = ws+96 (batch0 scores, 32 MiB -> spans 96..128, covering
    // WQT/BIAS/XLNB AND FF2 regions until its last read at PV), SL1 = d_out.
    // QK^T once (z=2, 2048 blocks); PV once (z=4, 1024 blocks). PV partials
    // -> P0(XB) + QP; dirty HB span = 32 MiB (R6 lesson).
    // RS (fp32 row sums, 32 KB) at VP: VP dead after tr_bf16; zeroed by a
    // fill dispatch AFTER tr_bf16 (VP is the transpose SOURCE — R10's NaN
    // came from violating this liveness chain). FF1's HB write covers VP
    // only after LN6's last read of RS (stream-ordered: safe).
    char* ws = (char*)d_ws;
    __bf16* W1T = (__bf16*)(ws);
    __bf16* W2T = (__bf16*)(ws + 8 * MB);
    __bf16* XB  = (__bf16*)(ws + 16 * MB);
    __bf16* P0  = XB;
    __bf16* QP  = (__bf16*)(ws + 32 * MB);
    __bf16* KP  = (__bf16*)(ws + 48 * MB);
    __bf16* VP  = (__bf16*)(ws + 64 * MB);
    __bf16* VT  = (__bf16*)(ws + 80 * MB);
    __bf16* FF  = VT;
    __bf16* HB  = XB;                        // 64 MiB span, used post-LN6
    __bf16* SL0 = (__bf16*)(ws + 96 * MB);
    __bf16* WQT = (__bf16*)(ws + 96 * MB);
    float*  BIAS= (float*)(ws + 96 * MB + 6 * MB);
    __bf16* XLNB= (__bf16*)(ws + 96 * MB);
    __bf16* FF2 = (__bf16*)(ws + 112 * MB);
    __bf16* SL1 = (__bf16*)out;              // 32 MiB scratch slab (tier1)

    int Rs;
    if (ws_size >= 128 * MB)      Rs = 4096;
    else if (ws_size >= 112 * MB) Rs = 2048;
    else {
        fill_diag<<<dim3((out_size + 255) / 256), dim3(256), 0, stream>>>(
            out, (float)(ws_size >> 20), out_size);
        return;
    }
    float* RS = (Rs == 4096) ? (float*)VP : out;  // tier2: RS in d_out

    const dim3 t256(256);
    const dim3 t32x8(32, 8);

    // stage 0: mega-prep (conv + 5 transposes + bias pack)
    prep<<<dim3(8192 + 1 + 3072 + 4096 + 4096), t256, 0, stream>>>(
        X, XB, Wq, Wk, Wv, WQT, W1, W1T, W2, W2T, bq, bk, bv, BIAS);

    // stage 1: fused QKV projections, z = {q,k,v} -> QP/KP/VP
    gemm_nt<<<dim3(D / 128, M / 128, 3), t256, 0, stream>>>(
        XB, WQT, QP, BIAS, nullptr, nullptr, D, D, D, D,
        0, (long)D * D, (long)M * D, D, 0, 0.f);

    // stage 2: V^T per batch [D,S]
    tr_bf16<<<dim3(D / 32, S / 32, 2), t32x8, 0, stream>>>(VP, VT, S, D);

    // zero fused-softmax row sums (MUST be after tr_bf16: RS aliases VP)
    fill_diag<<<dim3(M / 256), t256, 0, stream>>>(RS, 0.f, M);

    // stages 3-5: attention (quirk: queries<-KP, keys<-QP); QK^T ep=4 fuses
    // exp + rowsum (softmax pass eliminated; normalization folded into LN6).
    if (Rs == 4096) {
        // merged QK^T, both batches in one 2048-block dispatch:
        // z=0 -> SL0, z=1 -> SL1 (d_out) + rowsum offset S
        gemm_nt<<<dim3(S / 128, S / 128, 2), t256, 0, stream>>>(
            KP, QP, SL0, nullptr, RS, SL1,
            D, D, D, S, (long)S * D, (long)S * D, 0, (long)S, 4, 0.03125f);
        // PV combined, ep=6: z=(b<<1)|ks -> 1024 blocks (4/CU).
        // A = SL0/SL1 + ks*2048; B = VT + b*DS + ks*2048; C = P_ks + b*SD.
        gemm_nt<<<dim3(D / 128, S / 128, 4), t256, 0, stream>>>(
            SL0, VT, P0, nullptr, nullptr, SL1,
            S / 2, S, S, D,
            (long)(S / 2), (long)D * S, (long)(QP - P0), (long)S * D,
            6, 0.f);
    } else {
        // tier2 fallback: per-chunk QK -> SL0 (16 MiB slab), PV split-K=2
        // partials -> P0 / VP (RS lives in d_out here).
        const long sCpv = (long)(VP - P0);
        for (int b = 0; b < 2; ++b) {
            for (int c = 0; c < S / Rs; ++c) {
                const __bf16* Ak = KP + (size_t)(b * S + c * Rs) * D;
                gemm_nt<<<dim3(S / 128, Rs / 128), t256, 0, stream>>>(
                    Ak, QP + (size_t)b * S * D, SL0, nullptr,
                    RS + (size_t)b * S + c * Rs, nullptr,
                    D, D, D, S, 0, 0, 0, 0, 4, 0.03125f);
                gemm_nt<<<dim3(D / 128, Rs / 128, 2), t256, 0, stream>>>(
                    SL0, VT + (size_t)b * D * S, P0 + (size_t)(b * S + c * Rs) * D,
                    nullptr, nullptr, nullptr,
                    S / 2, S, S, D, S / 2, S / 2, sCpv, 0, 0, 0.f);
            }
        }
    }

    // stage 6: x = LN(input + (P0 + P1)/rowsum) -> bf16
    if (Rs == 4096) {
        ln_residual<<<dim3(M), t256, 0, stream>>>(
            X, nullptr, P0, QP, nullptr, RS, gamma, beta, nullptr, XLNB);
    } else {
        ln_residual<<<dim3(M), t256, 0, stream>>>(
            X, nullptr, P0, VP, nullptr, RS, gamma, beta, nullptr, XLNB);
    }

    // stage 7: h = gelu(x @ W1 + b1)
    gemm_nt<<<dim3(H / 128, M / 128), t256, 0, stream>>>(
        XLNB, W1T, HB, b1, nullptr, nullptr, D, D, D, H, 0, 0, 0, 0, 3, 0.f);

    // stage 8 + 9
    if (Rs == 4096) {
        // split-K=2: partials to FF / FF2 (no bias; b2 added in LN)
        gemm_nt<<<dim3(D / 128, M / 128, 2), t256, 0, stream>>>(
            HB, W2T, FF, nullptr, nullptr, nullptr, H / 2, H, H, D,
            H / 2, H / 2, (long)(FF2 - FF), 0, 1, 1.0f);
        ln_residual<<<dim3(M), t256, 0, stream>>>(
            nullptr, XLNB, FF, FF2, b2, nullptr, gamma, beta, out, nullptr);
    } else {
        gemm_nt<<<dim3(D / 128, M / 128), t256, 0, stream>>>(
            HB, W2T, FF, b2, nullptr, nullptr, H, H, H, D, 0, 0, 0, 0, 0, 0.f);
        ln_residual<<<dim3(M), t256, 0, stream>>>(
            nullptr, XLNB, FF, nullptr, nullptr, nullptr, gamma, beta, out, nullptr);
    }
}